// Round 15
// baseline (717.600 us; speedup 1.0000x reference)
//
#include <hip/hip_runtime.h>
#include <cstdint>
#include <cstddef>

// Round 14: R13 regressed (halved cols doubled A-staging; conflicts 2x) ->
// REVERT poolm to exact R12. New fast path: k2 stored as fp16 (k2h) by k_k2m
// (low half ALIASES dead k1 buffer, high half +67MB fresh, runtime-checked);
// k_poole2 streams k2h (no GEMM): exp once/elem, LDS 128-row chunks, register
// pool accum, 1 atomic dump/block, 49KB LDS. Fallbacks: R12 poolm (no k2h),
// fp32 path (no fp16 region).

#define DI __device__ __forceinline__

constexpr int   Bn    = 16;
constexpr int   Ln    = 8192;
constexpr int   Nn    = Bn * Ln;   // 131072
constexpr float EPSBN = 1e-5f;

typedef _Float16 f16;
typedef f16  half8 __attribute__((ext_vector_type(8)));
typedef float f32x4 __attribute__((ext_vector_type(4)));
#define MFMA16(a,b,c) __builtin_amdgcn_mfma_f32_16x16x32_f16(a,b,c,0,0,0)

DI unsigned f2ord(float f){
  unsigned u = __float_as_uint(f);
  return (u & 0x80000000u) ? ~u : (u | 0x80000000u);
}
DI float ord2f(unsigned o){
  unsigned u = (o & 0x80000000u) ? (o & 0x7fffffffu) : ~o;
  return __uint_as_float(u);
}
// swizzled LDS address for fp16 tile [*][128] (pitch 256B), 16B-granule XOR
DI char* swz(char* base, int row, int k){
  unsigned byte = (unsigned)(row*256 + k*2);
  byte ^= (unsigned)((row & 7) << 4);
  return base + byte;
}

// ---------------------------------------------------------------- init
__global__ void k_init(float* z, int n){
  int i = blockIdx.x * 256 + threadIdx.x;
  int stride = gridDim.x * 256;
  for (; i < n; i += stride) z[i] = 0.f;
}
__global__ void k_initu(unsigned* z, unsigned pat, int n){
  int i = blockIdx.x * 256 + threadIdx.x;
  int stride = gridDim.x * 256;
  for (; i < n; i += stride) z[i] = pat;
}

// ---------------------------------------------------------------- po layer 1
__global__ __launch_bounds__(256) void k_po1(
    const float* __restrict__ x, const float* __restrict__ w1, const float* __restrict__ b1,
    float* __restrict__ h1, float* __restrict__ s16, float* __restrict__ cmean){
  __shared__ __align__(16) float ws[512];
  __shared__ float bs[16];
  __shared__ float hs[256][17];
  __shared__ float xs[256][33];
  const int t = threadIdx.x;
  for (int i = t; i < 512; i += 256) ws[i] = w1[i];
  if (t < 16) bs[t] = b1[t];
  const int n = blockIdx.x * 256 + t;
  float xr[32];
  const float4* xp = (const float4*)(x + (size_t)n * 32);
#pragma unroll
  for (int i = 0; i < 8; ++i){
    float4 v = xp[i];
    xr[4*i+0] = v.x; xr[4*i+1] = v.y; xr[4*i+2] = v.z; xr[4*i+3] = v.w;
    xs[t][4*i+0] = v.x; xs[t][4*i+1] = v.y; xs[t][4*i+2] = v.z; xs[t][4*i+3] = v.w;
  }
  __syncthreads();
  float h[16];
#pragma unroll
  for (int o = 0; o < 16; ++o){
    float a = bs[o];
#pragma unroll
    for (int c = 0; c < 32; ++c) a = fmaf(ws[o*32 + c], xr[c], a);
    h[o] = a;
    hs[t][o] = a;
  }
  float4* hp = (float4*)(h1 + (size_t)n * 16);
#pragma unroll
  for (int i = 0; i < 4; ++i) hp[i] = make_float4(h[4*i], h[4*i+1], h[4*i+2], h[4*i+3]);
  __syncthreads();
  if (t < 16){
    float s = 0.f, q = 0.f;
    for (int r = 0; r < 256; ++r){ float v = hs[r][t]; s += v; q = fmaf(v, v, q); }
    atomicAdd(&s16[t], s);
    atomicAdd(&s16[16 + t], q);
  } else if (t >= 32 && t < 64){
    const int c = t - 32;
    float s = 0.f;
    for (int r = 0; r < 256; ++r) s += xs[r][c];
    const int b = blockIdx.x >> 5;
    atomicAdd(&cmean[b*32 + c], s);
  }
}

// ---------------------------------------------------------------- po layer 2
__global__ __launch_bounds__(256) void k_po2(
    const float* __restrict__ h1, const float* __restrict__ s16,
    const float* __restrict__ g1, const float* __restrict__ be1,
    const float* __restrict__ w2, const float* __restrict__ b2,
    float* __restrict__ pvec, float* __restrict__ s2v){
  __shared__ float sc[16], sh[16], w2s[16];
  __shared__ float as_[256];
  const int t = threadIdx.x;
  if (t < 16){
    float mu  = s16[t]    * (1.f/Nn);
    float var = fmaxf(s16[16+t] * (1.f/Nn) - mu*mu, 0.f);
    float s = g1[t] * rsqrtf(var + EPSBN);
    sc[t] = s; sh[t] = be1[t] - mu*s;
    w2s[t] = w2[t];
  }
  __syncthreads();
  const int n = blockIdx.x * 256 + t;
  const float* hp = h1 + (size_t)n * 16;
  float a = b2[0];
#pragma unroll
  for (int o = 0; o < 16; ++o)
    a = fmaf(fmaxf(hp[o]*sc[o] + sh[o], 0.f), w2s[o], a);
  pvec[n] = a;
  as_[t] = a;
  __syncthreads();
  if (t == 0){
    float s = 0.f, q = 0.f;
    for (int r = 0; r < 256; ++r){ float v = as_[r]; s += v; q = fmaf(v, v, q); }
    atomicAdd(&s2v[0], s); atomicAdd(&s2v[1], q);
  }
}

// ------------- per-segment: catt MLP + p softmax (MAX-SHIFTED) denom
__global__ __launch_bounds__(256) void k_pseg(
    float* __restrict__ pvec, const float* __restrict__ s2v,
    const float* __restrict__ g2, const float* __restrict__ be2,
    const float* __restrict__ cmean,
    const float* __restrict__ cw1, const float* __restrict__ cb1,
    const float* __restrict__ cw2, const float* __restrict__ cb2,
    float* __restrict__ catt, float* __restrict__ Zp){
  __shared__ float cm[32], t1[16], t2[32], red[256], scsh[2], pms;
  const int t = threadIdx.x, b = blockIdx.x;
  if (t == 0){
    float mu  = s2v[0] * (1.f/Nn);
    float var = fmaxf(s2v[1] * (1.f/Nn) - mu*mu, 0.f);
    float s = g2[0] * rsqrtf(var + EPSBN);
    scsh[0] = s; scsh[1] = be2[0] - mu*s;
  }
  if (t < 32) cm[t] = cmean[b*32 + t] * (1.f/Ln);
  __syncthreads();
  if (t < 16){
    float a = cb1[t];
#pragma unroll
    for (int c = 0; c < 32; ++c) a = fmaf(cw1[t*32 + c], cm[c], a);
    t1[t] = fmaxf(a, 0.f);
  }
  __syncthreads();
  if (t < 32){
    float a = cb2[t];
#pragma unroll
    for (int o = 0; o < 16; ++o) a = fmaf(cw2[t*16 + o], t1[o], a);
    t2[t] = fmaxf(a, 0.f);
  }
  __syncthreads();
  if (t < 32){
    float mx = -1e30f;
#pragma unroll
    for (int j = 0; j < 32; ++j) mx = fmaxf(mx, t2[j]);
    float sm = 0.f;
#pragma unroll
    for (int j = 0; j < 32; ++j) sm += expf(t2[j] - mx);
    catt[b*32 + t] = expf(t2[t] - mx) / sm;
  }
  const float sc = scsh[0], sh = scsh[1];
  float mx = 0.f;
  for (int i = 0; i < Ln/256; ++i){
    int n = b*Ln + i*256 + t;
    float p = fmaxf(pvec[n]*sc + sh, 0.f);
    mx = fmaxf(mx, p);
  }
  red[t] = mx; __syncthreads();
  for (int s = 128; s > 0; s >>= 1){
    if (t < s) red[t] = fmaxf(red[t], red[t+s]);
    __syncthreads();
  }
  if (t == 0) pms = red[0];
  __syncthreads();
  const float pm = pms;
  float acc = 0.f;
  for (int i = 0; i < Ln/256; ++i){
    int n = b*Ln + i*256 + t;
    float p = fmaxf(pvec[n]*sc + sh, 0.f);
    float e = expf(p - pm);
    pvec[n] = e;
    acc += e;
  }
  __syncthreads();
  red[t] = acc; __syncthreads();
  for (int s = 128; s > 0; s >>= 1){
    if (t < s) red[t] += red[t+s];
    __syncthreads();
  }
  if (t == 0) Zp[b] = red[0];
}

// ------------------------------------------- flt = gated x ; k1 = flt@k_w1^T (fp32)
__global__ __launch_bounds__(256) void k_fltk1(
    const float* __restrict__ x, const float* __restrict__ pvec,
    const float* __restrict__ Zp, const float* __restrict__ catt,
    const float* __restrict__ kw1, const float* __restrict__ kb1,
    float* __restrict__ flt, float* __restrict__ k1){
  __shared__ __align__(16) float ws[4096];
  __shared__ float kb[128], ca[32];
  const int t = threadIdx.x;
  for (int i = t; i < 4096; i += 256) ws[i] = kw1[i];
  if (t < 128) kb[t] = kb1[t];
  const int b = blockIdx.x >> 5;
  if (t < 32) ca[t] = catt[b*32 + t];
  __syncthreads();
  const int n = blockIdx.x * 256 + t;
  const float w = pvec[n] * (1e7f / Zp[b]);
  float fr[32];
  const float4* xp = (const float4*)(x + (size_t)n * 32);
  float4* fp = (float4*)(flt + (size_t)n * 32);
#pragma unroll
  for (int i = 0; i < 8; ++i){
    float4 v = xp[i];
    float4 o;
    o.x = v.x * w * ca[4*i+0];
    o.y = v.y * w * ca[4*i+1];
    o.z = v.z * w * ca[4*i+2];
    o.w = v.w * w * ca[4*i+3];
    fp[i] = o;
    fr[4*i+0] = o.x; fr[4*i+1] = o.y; fr[4*i+2] = o.z; fr[4*i+3] = o.w;
  }
  float4* kp = (float4*)(k1 + (size_t)n * 128);
#pragma unroll
  for (int og = 0; og < 32; ++og){
    float a[4];
#pragma unroll
    for (int p = 0; p < 4; ++p){
      const int o = og*4 + p;
      float acc = kb[o];
#pragma unroll
      for (int c = 0; c < 32; ++c) acc = fmaf(ws[o*32 + c], fr[c], acc);
      a[p] = acc;
    }
    kp[og] = make_float4(a[0], a[1], a[2], a[3]);
  }
}

// ---------------------------------------------------------------- k1 stats (128 ch)
__global__ __launch_bounds__(256) void k_k1s(const float* __restrict__ k1, float* __restrict__ sk1){
  __shared__ float rs_[256], rq_[256];
  const int t = threadIdx.x;
  const int c = t & 127, half = t >> 7;
  const size_t rowbase = (size_t)blockIdx.x * 512;
  float sum = 0.f, ssq = 0.f;
  for (int i = 0; i < 256; ++i){
    float v = k1[(rowbase + half + (size_t)i*2) * 128 + c];
    sum += v; ssq = fmaf(v, v, ssq);
  }
  rs_[t] = sum; rq_[t] = ssq;
  __syncthreads();
  if (t < 128){
    atomicAdd(&sk1[c],       rs_[t] + rs_[t+128]);
    atomicAdd(&sk1[128 + c], rq_[t] + rq_[t+128]);
  }
}

// ---------------- r1f = fp16(relu(bn1(k1))) — normalized, fp16-safe
__global__ __launch_bounds__(256) void k_r1w(
    const float* __restrict__ k1, const float* __restrict__ sk1,
    const float* __restrict__ kg1, const float* __restrict__ kbe1,
    f16* __restrict__ r1f){
  __shared__ float sc1[128], sh1[128];
  const int t = threadIdx.x;
  if (t < 128){
    float mu  = sk1[t]     * (1.f/Nn);
    float var = fmaxf(sk1[128+t] * (1.f/Nn) - mu*mu, 0.f);
    float s = kg1[t] * rsqrtf(var + EPSBN);
    sc1[t] = s; sh1[t] = kbe1[t] - mu*s;
  }
  __syncthreads();
  const size_t n = (size_t)blockIdx.x * 128 + (t >> 1);
  const int k0 = (t & 1) * 64;
  const float4* kp = (const float4*)(k1 + n*128 + k0);
#pragma unroll
  for (int u = 0; u < 8; ++u){
    float4 a = kp[2*u], b = kp[2*u+1];
    const int kk = k0 + u*8;
    half8 h;
    h[0] = (f16)fmaxf(a.x*sc1[kk+0] + sh1[kk+0], 0.f);
    h[1] = (f16)fmaxf(a.y*sc1[kk+1] + sh1[kk+1], 0.f);
    h[2] = (f16)fmaxf(a.z*sc1[kk+2] + sh1[kk+2], 0.f);
    h[3] = (f16)fmaxf(a.w*sc1[kk+3] + sh1[kk+3], 0.f);
    h[4] = (f16)fmaxf(b.x*sc1[kk+4] + sh1[kk+4], 0.f);
    h[5] = (f16)fmaxf(b.y*sc1[kk+5] + sh1[kk+5], 0.f);
    h[6] = (f16)fmaxf(b.z*sc1[kk+6] + sh1[kk+6], 0.f);
    h[7] = (f16)fmaxf(b.w*sc1[kk+7] + sh1[kk+7], 0.f);
    *(half8*)&r1f[n*128 + kk] = h;
  }
}

// ---------------- w2h = fp16(w2)
__global__ __launch_bounds__(256) void k_w2h(const float* __restrict__ kw2, f16* __restrict__ w2h){
  const int i = (blockIdx.x * 256 + threadIdx.x) * 4;
#pragma unroll
  for (int u = 0; u < 4; ++u) w2h[i+u] = (f16)kw2[i+u];
}

// ---------------- MFMA pass 1: stats + extrema (+ optional fp16 k2 store)
__global__ __launch_bounds__(256) void k_k2m(
    const f16* __restrict__ r1f, const f16* __restrict__ w2h,
    float* __restrict__ S2, float* __restrict__ Q2,
    unsigned* __restrict__ amaxU, unsigned* __restrict__ aminU,
    f16* __restrict__ k2h_lo, f16* __restrict__ k2h_hi){
  __shared__ __align__(16) char U[65536];
  char* UA = U;
  char* UB = U + 32768;
  const int t = threadIdx.x;
  const int b = blockIdx.z;
  const int c0g = blockIdx.y * 128;
  const size_t rowbase = (size_t)b * Ln + (size_t)blockIdx.x * 128;
  {
    const int sr = t >> 1, k0 = (t & 1) * 64;
#pragma unroll
    for (int u = 0; u < 8; ++u){
      const int kk = k0 + u*8;
      *(uint4*)swz(UA, sr, kk) = *(const uint4*)&r1f[(rowbase + sr)*128 + kk];
      *(uint4*)swz(UB, sr, kk) = *(const uint4*)&w2h[(size_t)(c0g + sr)*128 + kk];
    }
  }
  __syncthreads();
  const int wid = t >> 6, lane = t & 63;
  const int wr = (wid & 1) * 64, wc = (wid >> 1) * 64;
  const int lrow = lane & 15, lk = (lane >> 4) * 8;
  f32x4 acc[4][4];
#pragma unroll
  for (int f = 0; f < 4; ++f)
#pragma unroll
    for (int g = 0; g < 4; ++g) acc[f][g] = (f32x4){0.f,0.f,0.f,0.f};
#pragma unroll
  for (int ks = 0; ks < 4; ++ks){
    half8 af[4], bf[4];
#pragma unroll
    for (int f = 0; f < 4; ++f) af[f] = *(half8*)swz(UA, wr + f*16 + lrow, ks*32 + lk);
#pragma unroll
    for (int g = 0; g < 4; ++g) bf[g] = *(half8*)swz(UB, wc + g*16 + lrow, ks*32 + lk);
#pragma unroll
    for (int f = 0; f < 4; ++f)
#pragma unroll
      for (int g = 0; g < 4; ++g)
        acc[f][g] = MFMA16(af[f], bf[g], acc[f][g]);
  }
  if (k2h_lo){   // store k2 as fp16 (lo half aliases dead k1; hi half fresh)
#pragma unroll
    for (int f = 0; f < 4; ++f)
#pragma unroll
      for (int g = 0; g < 4; ++g)
#pragma unroll
        for (int j = 0; j < 4; ++j){
          const size_t row = rowbase + (size_t)(wr + f*16 + (lane>>4)*4 + j);
          const int c = c0g + wc + g*16 + lrow;
          f16* dst = (row < (size_t)(Nn/2)) ? (k2h_lo + row*512 + c)
                                            : (k2h_hi + (row - Nn/2)*512 + c);
          *dst = (f16)acc[f][g][j];
        }
  }
#pragma unroll
  for (int g = 0; g < 4; ++g){
    float s = 0.f, q = 0.f, mx = -3.4e38f, mn = 3.4e38f;
#pragma unroll
    for (int f = 0; f < 4; ++f)
#pragma unroll
      for (int j = 0; j < 4; ++j){
        float a = acc[f][g][j];
        s += a; q = fmaf(a, a, q);
        mx = fmaxf(mx, a); mn = fminf(mn, a);
      }
    s += __shfl_xor(s, 16, 64);  s += __shfl_xor(s, 32, 64);
    q += __shfl_xor(q, 16, 64);  q += __shfl_xor(q, 32, 64);
    mx = fmaxf(mx, __shfl_xor(mx, 16, 64)); mx = fmaxf(mx, __shfl_xor(mx, 32, 64));
    mn = fminf(mn, __shfl_xor(mn, 16, 64)); mn = fminf(mn, __shfl_xor(mn, 32, 64));
    if (lane < 16){
      const int c = c0g + wc + g*16 + lane;
      atomicAdd(&S2[c], s);
      atomicAdd(&Q2[c], q);
      atomicMax(&amaxU[b*512 + c], f2ord(mx));
      atomicMin(&aminU[b*512 + c], f2ord(mn));
    }
  }
}

// --------------------------- finalize bn2 scale/shift per 512 ch (bias folded in)
__global__ __launch_bounds__(256) void k_k2fin(
    const float* __restrict__ S2, const float* __restrict__ Q2,
    const float* __restrict__ kb2, const float* __restrict__ kg2, const float* __restrict__ kbe2,
    float* __restrict__ sc2g, float* __restrict__ sh2g){
  const int c = blockIdx.x * 256 + threadIdx.x;
  float S = S2[c], Q = Q2[c], bb = kb2[c];
  float sum = S + (float)Nn * bb;
  float ssq = Q + 2.f*bb*S + (float)Nn * bb * bb;
  float mu  = sum * (1.f/Nn);
  float var = fmaxf(ssq * (1.f/Nn) - mu*mu, 0.f);
  float s = kg2[c] * rsqrtf(var + EPSBN);
  sc2g[c] = s;
  sh2g[c] = kbe2[c] + (bb - mu) * s;
}

// ---------------- pm[b,k] = max_r relu(bn2(k2)) from raw max/min extrema
__global__ void k_pmax(
    const unsigned* __restrict__ amaxU, const unsigned* __restrict__ aminU,
    const float* __restrict__ sc2g, const float* __restrict__ sh2g,
    float* __restrict__ pm){
  const int i = blockIdx.x * 256 + threadIdx.x;
  const int k = i & 511;
  float amax = ord2f(amaxU[i]), amin = ord2f(aminU[i]);
  float s = sc2g[k], h = sh2g[k];
  float p1 = fmaxf(amax*s + h, 0.f);
  float p2 = fmaxf(amin*s + h, 0.f);
  pm[i] = fmaxf(p1, p2);
}

// ---------------- STREAMING pool from stored fp16 k2 (fast path)
// grid (4 row-splits, 8 col-groups, 16 b); 256 thr; LDS 49KB -> 3 blocks/CU.
__global__ __launch_bounds__(256) void k_poole2(
    const f16* __restrict__ k2h_lo, const f16* __restrict__ k2h_hi,
    const float* __restrict__ flt,
    const float* __restrict__ sc2g, const float* __restrict__ sh2g,
    const float* __restrict__ pm,
    float* __restrict__ poolAcc, float* __restrict__ Z2){
  __shared__ __align__(16) float e2c[128*64];    // 32KB (also reused for reduction)
  __shared__ __align__(16) float fltc[128*33];   // 16.9KB (pitch 33, also z-partials)
  const int t = threadIdx.x;
  const int rs = blockIdx.x, cg = blockIdx.y, b = blockIdx.z;
  const int c0 = cg*64;
  // staging role: column-major e2 staging — thread owns col cst, 32 rows/wavepass
  const int cst = t & 63, rblk = t >> 6;          // 4 row-blocks of 32
  const float scT = sc2g[c0 + cst], shT = sh2g[c0 + cst], pmT = pm[b*512 + c0 + cst];
  // flt staging role
  const int srow = t >> 1, half = t & 1;
  // pool role
  const int cgrp = t & 15, chgrp = (t >> 4) & 3, rsub = t >> 6;
  float pacc[4][8];
#pragma unroll
  for (int ci = 0; ci < 4; ++ci)
#pragma unroll
    for (int j = 0; j < 8; ++j) pacc[ci][j] = 0.f;
  float zac[4] = {0.f,0.f,0.f,0.f};
  for (int ck = 0; ck < 16; ++ck){
    const size_t gr0 = (size_t)b*Ln + (size_t)rs*2048 + ck*128;
    __syncthreads();                   // prev pool reads retired
    // stage e2: thread computes col cst for rows rblk*32..+32 (exp once/elem)
    for (int i = 0; i < 32; ++i){
      const int r = rblk*32 + i;
      const size_t gr = gr0 + r;
      const f16* kp = (gr < (size_t)(Nn/2)) ? (k2h_lo + gr*512) : (k2h_hi + (gr - (size_t)(Nn/2))*512);
      float a = (float)kp[c0 + cst];
      float p = fmaxf(a*scT + shT, 0.f);
      e2c[r*64 + cst] = expf(p - pmT);
    }
    // stage flt: thread loads row srow, half 'half' (16 floats)
    {
      const float4* fp = (const float4*)&flt[(gr0 + srow)*32];
#pragma unroll
      for (int u = 0; u < 4; ++u)
        *(float4*)&fltc[srow*33 + half*16 + u*4] = fp[half*4 + u];
    }
    __syncthreads();
    // pool: thread (cgrp,chgrp,rsub) covers 4 cols x 8 ch over 32 rows
    const int r0 = rsub*32;
#pragma unroll 4
    for (int r = r0; r < r0 + 32; ++r){
      float4 ev = *(const float4*)&e2c[r*64 + cgrp*4];
      const float* fr = &fltc[r*33 + chgrp*8];
      float4 fa = *(const float4*)&fr[0];
      float4 fb = *(const float4*)&fr[4];
      pacc[0][0]=fmaf(ev.x,fa.x,pacc[0][0]); pacc[0][1]=fmaf(ev.x,fa.y,pacc[0][1]);
      pacc[0][2]=fmaf(ev.x,fa.z,pacc[0][2]); pacc[0][3]=fmaf(ev.x,fa.w,pacc[0][3]);
      pacc[0][4]=fmaf(ev.x,fb.x,pacc[0][4]); pacc[0][5]=fmaf(ev.x,fb.y,pacc[0][5]);
      pacc[0][6]=fmaf(ev.x,fb.z,pacc[0][6]); pacc[0][7]=fmaf(ev.x,fb.w,pacc[0][7]);
      pacc[1][0]=fmaf(ev.y,fa.x,pacc[1][0]); pacc[1][1]=fmaf(ev.y,fa.y,pacc[1][1]);
      pacc[1][2]=fmaf(ev.y,fa.z,pacc[1][2]); pacc[1][3]=fmaf(ev.y,fa.w,pacc[1][3]);
      pacc[1][4]=fmaf(ev.y,fb.x,pacc[1][4]); pacc[1][5]=fmaf(ev.y,fb.y,pacc[1][5]);
      pacc[1][6]=fmaf(ev.y,fb.z,pacc[1][6]); pacc[1][7]=fmaf(ev.y,fb.w,pacc[1][7]);
      pacc[2][0]=fmaf(ev.z,fa.x,pacc[2][0]); pacc[2][1]=fmaf(ev.z,fa.y,pacc[2][1]);
      pacc[2][2]=fmaf(ev.z,fa.z,pacc[2][2]); pacc[2][3]=fmaf(ev.z,fa.w,pacc[2][3]);
      pacc[2][4]=fmaf(ev.z,fb.x,pacc[2][4]); pacc[2][5]=fmaf(ev.z,fb.y,pacc[2][5]);
      pacc[2][6]=fmaf(ev.z,fb.z,pacc[2][6]); pacc[2][7]=fmaf(ev.z,fb.w,pacc[2][7]);
      pacc[3][0]=fmaf(ev.w,fa.x,pacc[3][0]); pacc[3][1]=fmaf(ev.w,fa.y,pacc[3][1]);
      pacc[3][2]=fmaf(ev.w,fa.z,pacc[3][2]); pacc[3][3]=fmaf(ev.w,fa.w,pacc[3][3]);
      pacc[3][4]=fmaf(ev.w,fb.x,pacc[3][4]); pacc[3][5]=fmaf(ev.w,fb.y,pacc[3][5]);
      pacc[3][6]=fmaf(ev.w,fb.z,pacc[3][6]); pacc[3][7]=fmaf(ev.w,fb.w,pacc[3][7]);
      if (chgrp == 0){ zac[0]+=ev.x; zac[1]+=ev.y; zac[2]+=ev.z; zac[3]+=ev.w; }
    }
  }
  // cross-rsub reduction via LDS, then one atomic dump
  __syncthreads();
#pragma unroll
  for (int ci = 0; ci < 4; ++ci)
#pragma unroll
    for (int j = 0; j < 8; ++j) e2c[t*32 + ci*8 + j] = pacc[ci][j];
#pragma unroll
  for (int ci = 0; ci < 4; ++ci) fltc[t*4 + ci] = zac[ci];
  __syncthreads();
  if (t < 64){
#pragma unroll
    for (int ci = 0; ci < 4; ++ci){
      const int c = c0 + cgrp*4 + ci;
#pragma unroll
      for (int j = 0; j < 8; ++j){
        float s = e2c[t*32 + ci*8 + j] + e2c[(t+64)*32 + ci*8 + j]
                + e2c[(t+128)*32 + ci*8 + j] + e2c[(t+192)*32 + ci*8 + j];
        atomicAdd(&poolAcc[((size_t)b*512 + c)*32 + chgrp*8 + j], s);
      }
      if (chgrp == 0){
        float z = fltc[t*4 + ci] + fltc[(t+64)*4 + ci]
                + fltc[(t+128)*4 + ci] + fltc[(t+192)*4 + ci];
        atomicAdd(&Z2[b*512 + c], z);
      }
    }
  }
}

// ---------------- MFMA pass 2 (R12 EXACT): 8-tile loop, 1 atomic dump (fallback)
__global__ __launch_bounds__(256) void k_poolm(
    const f16* __restrict__ r1f, const f16* __restrict__ w2h,
    const float* __restrict__ flt,
    const float* __restrict__ sc2g, const float* __restrict__ sh2g,
    const float* __restrict__ pm,
    float* __restrict__ poolAcc, float* __restrict__ Z2){
  __shared__ __align__(16) char U[65536];
  char* UA = U;
  char* UB = U + 32768;
  float* e2s  = (float*)U;
  float* flts = (float*)(U + 34816);
  const int t = threadIdx.x;
  const int b = blockIdx.z;
  const int c0g = blockIdx.y * 128;
  const int wid = t >> 6, lane = t & 63;
  const int wr = (wid & 1) * 64, wc = (wid >> 1) * 64;
  const int lrow = lane & 15, lk = (lane >> 4) * 8;
  const int cq = t & 15, hq = t >> 4;
  float sc2r[4], sh2r[4], pmr[4];
#pragma unroll
  for (int g = 0; g < 4; ++g){
    const int c = c0g + wc + g*16 + lrow;
    sc2r[g] = sc2g[c]; sh2r[g] = sh2g[c]; pmr[g] = pm[b*512 + c];
  }
  float pacc[2][4][2];
  float zacc[2][4];
#pragma unroll
  for (int H = 0; H < 2; ++H)
#pragma unroll
    for (int ci = 0; ci < 4; ++ci){
      pacc[H][ci][0] = 0.f; pacc[H][ci][1] = 0.f; zacc[H][ci] = 0.f;
    }
  for (int rt = 0; rt < 8; ++rt){
    const size_t rowbase = (size_t)b * Ln + ((size_t)blockIdx.x * 8 + rt) * 128;
    __syncthreads();
    {
      const int sr = t >> 1, k0 = (t & 1) * 64;
#pragma unroll
      for (int u = 0; u < 8; ++u){
        const int kk = k0 + u*8;
        *(uint4*)swz(UA, sr, kk) = *(const uint4*)&r1f[(rowbase + sr)*128 + kk];
        *(uint4*)swz(UB, sr, kk) = *(const uint4*)&w2h[(size_t)(c0g + sr)*128 + kk];
      }
    }
    __syncthreads();
    f32x4 acc[4][4];
#pragma unroll
    for (int f = 0; f < 4; ++f)
#pragma unroll
      for (int g = 0; g < 4; ++g) acc[f][g] = (f32x4){0.f,0.f,0.f,0.f};
#pragma unroll
    for (int ks = 0; ks < 4; ++ks){
      half8 af[4], bf[4];
#pragma unroll
      for (int f = 0; f < 4; ++f) af[f] = *(half8*)swz(UA, wr + f*16 + lrow, ks*32 + lk);
#pragma unroll
      for (int g = 0; g < 4; ++g) bf[g] = *(half8*)swz(UB, wc + g*16 + lrow, ks*32 + lk);
#pragma unroll
      for (int f = 0; f < 4; ++f)
#pragma unroll
        for (int g = 0; g < 4; ++g)
          acc[f][g] = MFMA16(af[f], bf[g], acc[f][g]);
    }
#pragma unroll
    for (int f = 0; f < 4; ++f)
#pragma unroll
      for (int g = 0; g < 4; ++g)
#pragma unroll
        for (int j = 0; j < 4; ++j){
          float p = fmaxf(acc[f][g][j]*sc2r[g] + sh2r[g], 0.f);
          acc[f][g][j] = expf(p - pmr[g]);
        }
    __syncthreads();
#pragma unroll
    for (int i = 0; i < 4; ++i){
      int lin = t + i*256;
      int r = lin >> 3, c4 = lin & 7;
      *(float4*)&flts[r*36 + c4*4] = *(const float4*)&flt[(rowbase + r)*32 + c4*4];
    }
    for (int H = 0; H < 2; ++H){
      if ((wid >> 1) == H){
#pragma unroll
        for (int f = 0; f < 4; ++f)
#pragma unroll
          for (int g = 0; g < 4; ++g)
#pragma unroll
            for (int j = 0; j < 4; ++j)
              e2s[(wr + f*16 + (lane>>4)*4 + j)*68 + g*16 + lrow] = acc[f][g][j];
      }
      __syncthreads();
#pragma unroll 4
      for (int r = 0; r < 128; ++r){
        float4 ev = *(const float4*)&e2s[r*68 + cq*4];
        float f0 = flts[r*36 + hq*2], f1 = flts[r*36 + hq*2 + 1];
        pacc[H][0][0]=fmaf(ev.x,f0,pacc[H][0][0]); pacc[H][0][1]=fmaf(ev.x,f1,pacc[H][0][1]);
        pacc[H][1][0]=fmaf(ev.y,f0,pacc[H][1][0]); pacc[H][1][1]=fmaf(ev.y,f1,pacc[H][1][1]);
        pacc[H][2][0]=fmaf(ev.z,f0,pacc[H][2][0]); pacc[H][2][1]=fmaf(ev.z,f1,pacc[H][2][1]);
        pacc[H][3][0]=fmaf(ev.w,f0,pacc[H][3][0]); pacc[H][3][1]=fmaf(ev.w,f1,pacc[H][3][1]);
        if (hq == 0){
          zacc[H][0]+=ev.x; zacc[H][1]+=ev.y; zacc[H][2]+=ev.z; zacc[H][3]+=ev.w;
        }
      }
      __syncthreads();
    }
  }
#pragma unroll
  for (int H = 0; H < 2; ++H)
#pragma unroll
    for (int ci = 0; ci < 4; ++ci){
      int c = c0g + H*64 + cq*4 + ci;
#pragma unroll
      for (int hj = 0; hj < 2; ++hj)
        atomicAdd(&poolAcc[((size_t)b*512 + c)*32 + hq*2 + hj], pacc[H][ci][hj]);
      if (hq == 0) atomicAdd(&Z2[b*512 + c], zacc[H][ci]);
    }
}

// ---------------- FALLBACK pass 1 (fp32 tiled GEMM stats)
__global__ __launch_bounds__(256) void k_k2sx(
    const float* __restrict__ k1, const float* __restrict__ kw2,
    const float* __restrict__ sk1, const float* __restrict__ kg1, const float* __restrict__ kbe1,
    float* __restrict__ S2, float* __restrict__ Q2,
    unsigned* __restrict__ amaxU, unsigned* __restrict__ aminU){
  __shared__ float sc1[128], sh1[128];
  __shared__ __align__(16) float r1t[64][68];
  __shared__ __align__(16) float w2t[64][68];
  const int t = threadIdx.x;
  const int chunk = blockIdx.x;
  const int cg    = blockIdx.y;
  const int b     = blockIdx.z;
  const int c0g = cg * 64;
  const size_t rowbase = (size_t)b * Ln + (size_t)chunk * 512;
  if (t < 128){
    float mu  = sk1[t]     * (1.f/Nn);
    float var = fmaxf(sk1[128+t] * (1.f/Nn) - mu*mu, 0.f);
    float s = kg1[t] * rsqrtf(var + EPSBN);
    sc1[t] = s; sh1[t] = kbe1[t] - mu*s;
  }
  const int ig = t & 15, jg = t >> 4;
  const int rr = t >> 2;
  const int ka4 = (t & 3) * 4;
  float csum[4] = {0.f,0.f,0.f,0.f}, cssq[4] = {0.f,0.f,0.f,0.f};
  float cmax[4] = {-3.4e38f,-3.4e38f,-3.4e38f,-3.4e38f};
  float cmin[4] = { 3.4e38f, 3.4e38f, 3.4e38f, 3.4e38f};
  for (int st = 0; st < 8; ++st){
    const size_t rb = rowbase + st*64;
    float acc[4][4];
#pragma unroll
    for (int i = 0; i < 4; ++i)
#pragma unroll
      for (int j = 0; j < 4; ++j) acc[i][j] = 0.f;
    for (int kb = 0; kb < 2; ++kb){
      __syncthreads();
#pragma unroll
      for (int u = 0; u < 4; ++u){
        const int kk = ka4 + u*16;
        const int ch = kb*64 + kk;
        float4 v = *(const float4*)&k1[(rb + rr)*128 + ch];
        r1t[kk+0][rr] = fmaxf(v.x*sc1[ch+0] + sh1[ch+0], 0.f);
        r1t[kk+1][rr] = fmaxf(v.y*sc1[ch+1] + sh1[ch+1], 0.f);
        r1t[kk+2][rr] = fmaxf(v.z*sc1[ch+2] + sh1[ch+2], 0.f);
        r1t[kk+3][rr] = fmaxf(v.w*sc1[ch+3] + sh1[ch+3], 0.f);
        float4 wv = *(const float4*)&kw2[(size_t)(c0g + rr)*128 + ch];
        w2t[kk+0][rr] = wv.x; w2t[kk+1][rr] = wv.y;
        w2t[kk+2][rr] = wv.z; w2t[kk+3][rr] = wv.w;
      }
      __syncthreads();
#pragma unroll 4
      for (int kk = 0; kk < 64; ++kk){
        float4 av = *(const float4*)&r1t[kk][ig*4];
        float4 bv = *(const float4*)&w2t[kk][jg*4];
        acc[0][0]=fmaf(av.x,bv.x,acc[0][0]); acc[0][1]=fmaf(av.x,bv.y,acc[0][1]);
        acc[0][2]=fmaf(av.x,bv.z,acc[0][2]); acc[0][3]=fmaf(av.x,bv.w,acc[0][3]);
        acc[1][0]=fmaf(av.y,bv.x,acc[1][0]); acc[1][1]=fmaf(av.y,bv.y,acc[1][1]);
        acc[1][2]=fmaf(av.y,bv.z,acc[1][2]); acc[1][3]=fmaf(av.y,bv.w,acc[1][3]);
        acc[2][0]=fmaf(av.z,bv.x,acc[2][0]); acc[2][1]=fmaf(av.z,bv.y,acc[2][1]);
        acc[2][2]=fmaf(av.z,bv.z,acc[2][2]); acc[2][3]=fmaf(av.z,bv.w,acc[2][3]);
        acc[3][0]=fmaf(av.w,bv.x,acc[3][0]); acc[3][1]=fmaf(av.w,bv.y,acc[3][1]);
        acc[3][2]=fmaf(av.w,bv.z,acc[3][2]); acc[3][3]=fmaf(av.w,bv.w,acc[3][3]);
      }
    }
#pragma unroll
    for (int j = 0; j < 4; ++j){
      float s4 = 0.f, q4 = 0.f;
#pragma unroll
      for (int i = 0; i < 4; ++i){
        float a = acc[i][j];
        s4 += a; q4 = fmaf(a, a, q4);
        cmax[j] = fmaxf(cmax[j], a);
        cmin[j] = fminf(cmin[j], a);
      }
      csum[j] += s4; cssq[j] += q4;
    }
  }
  float* redS  = &r1t[0][0];
  float* redQ  = &r1t[0][0] + 1024;
  float* redMx = &w2t[0][0];
  float* redMn = &w2t[0][0] + 1024;
  __syncthreads();
#pragma unroll
  for (int j = 0; j < 4; ++j){
    redS [ig*64 + jg*4 + j] = csum[j];
    redQ [ig*64 + jg*4 + j] = cssq[j];
    redMx[ig*64 + jg*4 + j] = cmax[j];
    redMn[ig*64 + jg*4 + j] = cmin[j];
  }
  __syncthreads();
  if (t < 64){
    float s = 0.f, q = 0.f, mx = -3.4e38f, mn = 3.4e38f;
#pragma unroll
    for (int i = 0; i < 16; ++i){
      s += redS[i*64 + t]; q += redQ[i*64 + t];
      mx = fmaxf(mx, redMx[i*64 + t]); mn = fminf(mn, redMn[i*64 + t]);
    }
    atomicAdd(&S2[c0g + t], s);
    atomicAdd(&Q2[c0g + t], q);
    atomicMax(&amaxU[b*512 + c0g + t], f2ord(mx));
    atomicMin(&aminU[b*512 + c0g + t], f2ord(mn));
  }
}

// ---------------- FALLBACK pass 2 (fp32 tiled GEMM + pool)
__global__ __launch_bounds__(256) void k_poolx(
    const float* __restrict__ k1, const float* __restrict__ flt,
    const float* __restrict__ kw2,
    const float* __restrict__ sk1, const float* __restrict__ kg1, const float* __restrict__ kbe1,
    const float* __restrict__ sc2g, const float* __restrict__ sh2g,
    const float* __restrict__ pm,
    float* __restrict__ poolAcc, float* __restrict__ Z2){
  __shared__ float sc1[128], sh1[128], sc2[64], sh2[64], pmL[64];
  __shared__ __align__(16) float r1t[64][68];
  __shared__ __align__(16) float w2t[64][68];
  __shared__ __align__(16) float e2s[64][68];
  __shared__ __align__(16) float flts[64][36];
  const int t = threadIdx.x;
  const int chunk = blockIdx.x;
  const int cg    = blockIdx.y;
  const int b     = blockIdx.z;
  const int c0g = cg * 64;
  const size_t rowbase = (size_t)b * Ln + (size_t)chunk * 512;
  if (t < 128){
    float mu  = sk1[t]     * (1.f/Nn);
    float var = fmaxf(sk1[128+t] * (1.f/Nn) - mu*mu, 0.f);
    float s = kg1[t] * rsqrtf(var + EPSBN);
    sc1[t] = s; sh1[t] = kbe1[t] - mu*s;
  } else if (t < 192){
    int c = t - 128;
    sc2[c] = sc2g[c0g + c];
    sh2[c] = sh2g[c0g + c];
    pmL[c] = pm[b*512 + c0g + c];
  }
  const int ig = t & 15, jg = t >> 4;
  const int cq = t & 15, hq = t >> 4;
  const int rr = t >> 2;
  const int ka4 = (t & 3) * 4;
  float pacc[4][2] = {{0.f,0.f},{0.f,0.f},{0.f,0.f},{0.f,0.f}};
  float zacc[4] = {0.f,0.f,0.f,0.f};
  for (int st = 0; st < 8; ++st){
    const size_t rb = rowbase + st*64;
    __syncthreads();
#pragma unroll
    for (int i = 0; i < 2; ++i){
      int lin = t + i*256;
      int r = lin >> 3, c4 = lin & 7;
      *(float4*)&flts[r][c4*4] = *(const float4*)&flt[(rb + r)*32 + c4*4];
    }
    float acc[4][4];
#pragma unroll
    for (int i = 0; i < 4; ++i)
#pragma unroll
      for (int j = 0; j < 4; ++j) acc[i][j] = 0.f;
    for (int kb = 0; kb < 2; ++kb){
      __syncthreads();
#pragma unroll
      for (int u = 0; u < 4; ++u){
        const int kk = ka4 + u*16;
        const int ch = kb*64 + kk;
        float4 v = *(const float4*)&k1[(rb + rr)*128 + ch];
        r1t[kk+0][rr] = fmaxf(v.x*sc1[ch+0] + sh1[ch+0], 0.f);
        r1t[kk+1][rr] = fmaxf(v.y*sc1[ch+1] + sh1[ch+1], 0.f);
        r1t[kk+2][rr] = fmaxf(v.z*sc1[ch+2] + sh1[ch+2], 0.f);
        r1t[kk+3][rr] = fmaxf(v.w*sc1[ch+3] + sh1[ch+3], 0.f);
        float4 wv = *(const float4*)&kw2[(size_t)(c0g + rr)*128 + ch];
        w2t[kk+0][rr] = wv.x; w2t[kk+1][rr] = wv.y;
        w2t[kk+2][rr] = wv.z; w2t[kk+3][rr] = wv.w;
      }
      __syncthreads();
#pragma unroll 4
      for (int kk = 0; kk < 64; ++kk){
        float4 av = *(const float4*)&r1t[kk][ig*4];
        float4 bv = *(const float4*)&w2t[kk][jg*4];
        acc[0][0]=fmaf(av.x,bv.x,acc[0][0]); acc[0][1]=fmaf(av.x,bv.y,acc[0][1]);
        acc[0][2]=fmaf(av.x,bv.z,acc[0][2]); acc[0][3]=fmaf(av.x,bv.w,acc[0][3]);
        acc[1][0]=fmaf(av.y,bv.x,acc[1][0]); acc[1][1]=fmaf(av.y,bv.y,acc[1][1]);
        acc[1][2]=fmaf(av.y,bv.z,acc[1][2]); acc[1][3]=fmaf(av.y,bv.w,acc[1][3]);
        acc[2][0]=fmaf(av.z,bv.x,acc[2][0]); acc[2][1]=fmaf(av.z,bv.y,acc[2][1]);
        acc[2][2]=fmaf(av.z,bv.z,acc[2][2]); acc[2][3]=fmaf(av.z,bv.w,acc[2][3]);
        acc[3][0]=fmaf(av.w,bv.x,acc[3][0]); acc[3][1]=fmaf(av.w,bv.y,acc[3][1]);
        acc[3][2]=fmaf(av.w,bv.z,acc[3][2]); acc[3][3]=fmaf(av.w,bv.w,acc[3][3]);
      }
    }
#pragma unroll
    for (int i = 0; i < 4; ++i){
      int r = ig*4 + i;
#pragma unroll
      for (int j = 0; j < 4; ++j){
        int c = jg*4 + j;
        float p = fmaxf(acc[i][j]*sc2[c] + sh2[c], 0.f);
        e2s[r][c] = expf(p - pmL[c]);
      }
    }
    __syncthreads();
#pragma unroll 4
    for (int r = 0; r < 64; ++r){
      float4 ev = *(const float4*)&e2s[r][cq*4];
      float f0 = flts[r][hq*2], f1 = flts[r][hq*2 + 1];
      pacc[0][0]=fmaf(ev.x,f0,pacc[0][0]); pacc[0][1]=fmaf(ev.x,f1,pacc[0][1]);
      pacc[1][0]=fmaf(ev.y,f0,pacc[1][0]); pacc[1][1]=fmaf(ev.y,f1,pacc[1][1]);
      pacc[2][0]=fmaf(ev.z,f0,pacc[2][0]); pacc[2][1]=fmaf(ev.z,f1,pacc[2][1]);
      pacc[3][0]=fmaf(ev.w,f0,pacc[3][0]); pacc[3][1]=fmaf(ev.w,f1,pacc[3][1]);
      if (hq == 0){ zacc[0]+=ev.x; zacc[1]+=ev.y; zacc[2]+=ev.z; zacc[3]+=ev.w; }
    }
  }
#pragma unroll
  for (int ci = 0; ci < 4; ++ci){
    int c = c0g + cq*4 + ci;
#pragma unroll
    for (int hj = 0; hj < 2; ++hj)
      atomicAdd(&poolAcc[((size_t)b*512 + c)*32 + hq*2 + hj], pacc[ci][hj]);
    if (hq == 0) atomicAdd(&Z2[b*512 + c], zacc[ci]);
  }
}

// ---------------------------------------------------------------- out2 finalize
__global__ __launch_bounds__(256) void k_out2(
    const float* __restrict__ poolAcc, const float* __restrict__ Z2, float* __restrict__ out2){
  const int i = blockIdx.x * 256 + threadIdx.x;
  const int k = (i >> 5) & 511;
  const int b = i >> 14;
  out2[i] = poolAcc[i] / (Z2[b*512 + k] * (float)Ln);
}

// ---------------------------------------------------------------- FC1 (+BN over b, relu)
__global__ __launch_bounds__(256) void k_fc1(
    const float* __restrict__ out2, const float* __restrict__ w1, const float* __restrict__ b1,
    const float* __restrict__ g1, const float* __restrict__ be1, float* __restrict__ rfc1){
  __shared__ float red[256];
  __shared__ float pre[16];
  __shared__ float scsh[2];
  const int ch = blockIdx.x;
  const int t  = threadIdx.x;
  float acc[16];
#pragma unroll
  for (int bb = 0; bb < 16; ++bb) acc[bb] = 0.f;
  for (int k = t; k < 16384; k += 256){
    float w = w1[(size_t)ch*16384 + k];
#pragma unroll
    for (int bb = 0; bb < 16; ++bb)
      acc[bb] = fmaf(out2[(size_t)bb*16384 + k], w, acc[bb]);
  }
  for (int bb = 0; bb < 16; ++bb){
    red[t] = acc[bb]; __syncthreads();
    for (int s = 128; s > 0; s >>= 1){
      if (t < s) red[t] += red[t+s];
      __syncthreads();
    }
    if (t == 0) pre[bb] = red[0] + b1[ch];
    __syncthreads();
  }
  if (t == 0){
    float m = 0.f, qv = 0.f;
#pragma unroll
    for (int bb = 0; bb < 16; ++bb){ float v = pre[bb]; m += v; qv = fmaf(v, v, qv); }
    m *= (1.f/16.f); qv = fmaxf(qv*(1.f/16.f) - m*m, 0.f);
    float s = g1[ch] * rsqrtf(qv + EPSBN);
    scsh[0] = s; scsh[1] = be1[ch] - m*s;
  }
  __syncthreads();
  if (t < 16)
    rfc1[(size_t)t*512 + ch] = fmaxf(pre[t]*scsh[0] + scsh[1], 0.f);
}

// ---------------------------------------------------------------- FC2 (+BN over b, no relu)
__global__ __launch_bounds__(128) void k_fc2(
    const float* __restrict__ rfc1, const float* __restrict__ w2, const float* __restrict__ b2,
    const float* __restrict__ g2, const float* __restrict__ be2, float* __restrict__ rfc2){
  __shared__ float pre[8][16];
  __shared__ float scB[8], shB[8];
  const int t = threadIdx.x;
  const int bb = t & 15, jl = t >> 4;
  const int ch = blockIdx.x*8 + jl;
  float a = b2[ch];
  for (int k = 0; k < 512; ++k)
    a = fmaf(rfc1[(size_t)bb*512 + k], w2[(size_t)ch*512 + k], a);
  pre[jl][bb] = a;
  __syncthreads();
  if (t < 8){
    float m = 0.f, q = 0.f;
#pragma unroll
    for (int i = 0; i < 16; ++i){ float v = pre[t][i]; m += v; q = fmaf(v, v, q); }
    m *= (1.f/16.f); q = fmaxf(q*(1.f/16.f) - m*m, 0.f);
    float s = g2[blockIdx.x*8 + t] * rsqrtf(q + EPSBN);
    scB[t] = s; shB[t] = be2[blockIdx.x*8 + t] - m*s;
  }
  __syncthreads();
  rfc2[(size_t)bb*256 + ch] = pre[jl][bb]*scB[jl] + shB[jl];
}

// ---------------------------------------------------------------- final L2 normalize
__global__ __launch_bounds__(256) void k_fin(const float* __restrict__ rfc2, float* __restrict__ out){
  __shared__ float red[256];
  const int b = blockIdx.x, t = threadIdx.x;
  float v = rfc2[b*256 + t];
  red[t] = v*v; __syncthreads();
  for (int s = 128; s > 0; s >>= 1){
    if (t < s) red[t] += red[t+s];
    __syncthreads();
  }
  float nrm = sqrtf(red[0]);
  out[b*256 + t] = v / fmaxf(nrm, 1e-12f);
}

// ---------------- CONDITIONAL diagnostic (3000+code), clobbers only on failure
__global__ void k_diag3(
    const float* __restrict__ out2, const float* __restrict__ rfc1,
    const float* __restrict__ rfc2, float* __restrict__ out){
  if (blockIdx.x != 0 || threadIdx.x != 0) return;
  auto differs = [](float a, float b)->bool{
    return isfinite(a) && isfinite(b) &&
           fabsf(a - b) > 1e-7f*(fabsf(a) + fabsf(b)) + 1e-30f;
  };
  int code = 0;
  { bool ok = true;
    for (int j = 0; j < 512; ++j){
      size_t idx = ((size_t)j * 16411u + 13u) % ((size_t)Bn * 16384u);
      ok = ok && isfinite(out2[idx]);
    }
    if (ok) code += 128; }
  if (differs(out2[100*32 + 5], out2[100*32 + 17])) code += 64;
  if (differs(out2[100*32 + 5], out2[300*32 + 5])) code += 32;
  if (differs(out2[100*32 + 5], out2[(size_t)8*16384 + 100*32 + 5])) code += 16;
  { bool any = false;
    for (int i = 0; i < 512; ++i) if (fabsf(rfc1[i]) > 0.f){ any = true; break; }
    if (any) code += 8; }
  { bool any = false;
    for (int ch = 0; ch < 64; ++ch)
      any = any || differs(rfc1[ch], rfc1[(size_t)8*512 + ch]);
    if (any) code += 4; }
  { bool any = false;
    for (int t2 = 0; t2 < 256; ++t2)
      if (fabsf(rfc2[t2] - rfc2[8*256 + t2]) > 1e-12f){ any = true; break; }
    if (any) code += 2; }
  if (fabsf(out2[100*32 + 5]) > 1e-30f) code += 1;

  if (code != 255) out[0] = 3000.f + (float)code;
}

// ================================================================ host launcher
extern "C" void kernel_launch(void* const* d_in, const int* in_sizes, int n_in,
                              void* d_out, int out_size, void* d_ws, size_t ws_size,
                              hipStream_t stream){
  (void)in_sizes; (void)n_in; (void)out_size;
  const float* x      = (const float*)d_in[0];
  const float* po_w1  = (const float*)d_in[2];
  const float* po_b1  = (const float*)d_in[3];
  const float* po_g1  = (const float*)d_in[4];
  const float* po_be1 = (const float*)d_in[5];
  const float* po_w2  = (const float*)d_in[6];
  const float* po_b2  = (const float*)d_in[7];
  const float* po_g2  = (const float*)d_in[8];
  const float* po_be2 = (const float*)d_in[9];
  const float* ch_w1  = (const float*)d_in[10];
  const float* ch_b1  = (const float*)d_in[11];
  const float* ch_w2  = (const float*)d_in[12];
  const float* ch_b2  = (const float*)d_in[13];
  const float* k_w1   = (const float*)d_in[14];
  const float* k_b1   = (const float*)d_in[15];
  const float* k_g1   = (const float*)d_in[16];
  const float* k_be1  = (const float*)d_in[17];
  const float* k_w2   = (const float*)d_in[18];
  const float* k_b2   = (const float*)d_in[19];
  const float* k_g2   = (const float*)d_in[20];
  const float* k_be2  = (const float*)d_in[21];
  const float* fc_w1  = (const float*)d_in[22];
  const float* fc_b1  = (const float*)d_in[23];
  const float* fc_g1  = (const float*)d_in[24];
  const float* fc_be1 = (const float*)d_in[25];
  const float* fc_w2  = (const float*)d_in[26];
  const float* fc_b2  = (const float*)d_in[27];
  const float* fc_g2  = (const float*)d_in[28];
  const float* fc_be2 = (const float*)d_in[29];

  char* base = (char*)d_ws;
  size_t off = 0;
  auto alloc = [&](size_t bytes) -> char* {
    char* p = base + off;
    off = (off + bytes + 255) & ~(size_t)255;
    return p;
  };
  float* h1   = (float*)alloc((size_t)Nn * 16 * 4);
  float* pvec = (float*)alloc((size_t)Nn * 4);
  float* flt  = (float*)alloc((size_t)Nn * 32 * 4);
  float* k1   = (float*)alloc((size_t)Nn * 128 * 4);   // 67.1MB; dead after r1w -> aliased by k2h_lo
  // ---- zeroed accumulator region (contiguous) ----
  char* zbase = base + off;
  float*    s16     = (float*)alloc(32 * 4);
  float*    s2v     = (float*)alloc(2 * 4);
  float*    cmean   = (float*)alloc(512 * 4);
  float*    sk1     = (float*)alloc(256 * 4);
  float*    S2      = (float*)alloc(512 * 4);
  float*    Q2      = (float*)alloc(512 * 4);
  float*    Z2      = (float*)alloc((size_t)Bn * 512 * 4);
  float*    poolAcc = (float*)alloc((size_t)Bn * 512 * 32 * 4);
  unsigned* amaxU   = (unsigned*)alloc((size_t)Bn * 512 * 4);
  char* zend = base + off;
  // ---- 0xFFFFFFFF-init region ----
  unsigned* aminU = (unsigned*)alloc((size_t)Bn * 512 * 4);
  // ---- written-before-read buffers ----
  float* catt  = (float*)alloc(512 * 4);
  float* Zp    = (float*)alloc(16 * 4);
  float* sc2g  = (float*)alloc(512 * 4);
  float* sh2g  = (float*)alloc(512 * 4);
  float* pm    = (float*)alloc((size_t)Bn * 512 * 4);
  float* out2  = (float*)alloc((size_t)Bn * 16384 * 4);
  float* rfc1  = (float*)alloc((size_t)Bn * 512 * 4);
  float* rfc2  = (float*)alloc((size_t)Bn * 256 * 4);
  if (off > ws_size) return;  // base workspace too small -> visible failure
  // ---- optional fp16 region (r1f + w2h), then optional k2h_hi ----
  f16* r1f = nullptr; f16* w2h = nullptr; f16* k2h_hi = nullptr;
  {
    size_t save = off;
    char* p1 = alloc((size_t)Nn * 128 * 2);
    char* p2 = alloc((size_t)512 * 128 * 2);
    if (off <= ws_size){ r1f = (f16*)p1; w2h = (f16*)p2; }
    else off = save;
  }
  if (r1f){
    size_t save = off;
    char* p3 = alloc((size_t)(Nn/2) * 512 * 2);   // 67.1MB
    if (off <= ws_size) k2h_hi = (f16*)p3;
    else off = save;
  }
  f16* k2h_lo = (f16*)k1;   // alias over dead k1 (valid: k1 reads all precede k_k2m)

  const int nzero = (int)((zend - zbase) / 4);
  hipLaunchKernelGGL(k_init,   dim3(64), dim3(256), 0, stream, (float*)zbase, nzero);
  hipLaunchKernelGGL(k_initu,  dim3(32), dim3(256), 0, stream, aminU, 0xFFFFFFFFu, Bn*512);
  hipLaunchKernelGGL(k_po1,    dim3(Nn/256), dim3(256), 0, stream, x, po_w1, po_b1, h1, s16, cmean);
  hipLaunchKernelGGL(k_po2,    dim3(Nn/256), dim3(256), 0, stream, h1, s16, po_g1, po_be1, po_w2, po_b2, pvec, s2v);
  hipLaunchKernelGGL(k_pseg,   dim3(Bn), dim3(256), 0, stream, pvec, s2v, po_g2, po_be2, cmean,
                     ch_w1, ch_b1, ch_w2, ch_b2, catt, Zp);
  hipLaunchKernelGGL(k_fltk1,  dim3(Nn/256), dim3(256), 0, stream, x, pvec, Zp, catt, k_w1, k_b1, flt, k1);
  hipLaunchKernelGGL(k_k1s,    dim3(Nn/512), dim3(256), 0, stream, k1, sk1);
  if (r1f){
    hipLaunchKernelGGL(k_r1w,  dim3(Nn/128), dim3(256), 0, stream, k1, sk1, k_g1, k_be1, r1f);
    hipLaunchKernelGGL(k_w2h,  dim3(64), dim3(256), 0, stream, k_w2, w2h);
    hipLaunchKernelGGL(k_k2m,  dim3(64, 4, Bn), dim3(256), 0, stream, r1f, w2h, S2, Q2, amaxU, aminU,
                       k2h_hi ? k2h_lo : (f16*)nullptr, k2h_hi);
    hipLaunchKernelGGL(k_k2fin, dim3(2), dim3(256), 0, stream, S2, Q2, k_b2, k_g2, k_be2, sc2g, sh2g);
    hipLaunchKernelGGL(k_pmax, dim3((Bn*512)/256), dim3(256), 0, stream, amaxU, aminU, sc2g, sh2g, pm);
    if (k2h_hi){
      hipLaunchKernelGGL(k_poole2, dim3(4, 8, Bn), dim3(256), 0, stream, k2h_lo, k2h_hi, flt,
                         sc2g, sh2g, pm, poolAcc, Z2);
    } else {
      hipLaunchKernelGGL(k_poolm, dim3(8, 4, Bn), dim3(256), 0, stream, r1f, w2h, flt,
                         sc2g, sh2g, pm, poolAcc, Z2);
    }
  } else {
    hipLaunchKernelGGL(k_k2sx, dim3(16, 8, Bn), dim3(256), 0, stream, k1, k_w2, sk1, k_g1, k_be1,
                       S2, Q2, amaxU, aminU);
    hipLaunchKernelGGL(k_k2fin, dim3(2), dim3(256), 0, stream, S2, Q2, k_b2, k_g2, k_be2, sc2g, sh2g);
    hipLaunchKernelGGL(k_pmax, dim3((Bn*512)/256), dim3(256), 0, stream, amaxU, aminU, sc2g, sh2g, pm);
    hipLaunchKernelGGL(k_poolx, dim3(16, 8, Bn), dim3(256), 0, stream, k1, flt, k_w2, sk1, k_g1, k_be1,
                       sc2g, sh2g, pm, poolAcc, Z2);
  }
  hipLaunchKernelGGL(k_out2,   dim3((Bn*16384)/256), dim3(256), 0, stream, poolAcc, Z2, out2);
  hipLaunchKernelGGL(k_fc1,    dim3(512), dim3(256), 0, stream, out2, fc_w1, fc_b1, fc_g1, fc_be1, rfc1);
  hipLaunchKernelGGL(k_fc2,    dim3(32), dim3(128), 0, stream, rfc1, fc_w2, fc_b2, fc_g2, fc_be2, rfc2);
  hipLaunchKernelGGL(k_fin,    dim3(Bn), dim3(256), 0, stream, rfc2, (float*)d_out);
  hipLaunchKernelGGL(k_diag3,  dim3(1), dim3(64), 0, stream, out2, rfc1, rfc2, (float*)d_out);
}

// Round 16
// 429.345 us; speedup vs baseline: 1.6714x; 1.6714x over previous
//
#include <hip/hip_runtime.h>
#include <cstdint>
#include <cstddef>

// Round 15: pool phase as MFMA. R13/R14 lesson: narrow scalar memory paths
// lose to dense MFMA. pooled[c][ch] = sum_r e2[r][c]*flt[r][ch] IS a GEMM:
//  * k_poolm v3: GEMM frags read DIRECT FROM GLOBAL (L2-resident r1f/w2h,
//    aligned half8) -> no UA/UB staging, 2 barriers/tile; exp in regs; e2^T
//    -> LDS fp16 [col][row] pitch 136 (half4-packed); flt -> fp16 [ch][row]
//    scaled 2^-9 (range-safe, power-of-2); PV = 16 MFMA/wave, accumulators
//    persist across 8 tiles, x512 at single atomic dump. LDS 43.5KB.
//  * k_k2m v2: same direct-global frags (bit-identical K-chain -> pm exact).
//  * poole2/k2h path deleted; fp32 fallback path intact.

#define DI __device__ __forceinline__

constexpr int   Bn    = 16;
constexpr int   Ln    = 8192;
constexpr int   Nn    = Bn * Ln;   // 131072
constexpr float EPSBN = 1e-5f;

typedef _Float16 f16;
typedef f16  half8 __attribute__((ext_vector_type(8)));
typedef f16  half4 __attribute__((ext_vector_type(4)));
typedef float f32x4 __attribute__((ext_vector_type(4)));
#define MFMA16(a,b,c) __builtin_amdgcn_mfma_f32_16x16x32_f16(a,b,c,0,0,0)

DI unsigned f2ord(float f){
  unsigned u = __float_as_uint(f);
  return (u & 0x80000000u) ? ~u : (u | 0x80000000u);
}
DI float ord2f(unsigned o){
  unsigned u = (o & 0x80000000u) ? (o & 0x7fffffffu) : ~o;
  return __uint_as_float(u);
}

// ---------------------------------------------------------------- init
__global__ void k_init(float* z, int n){
  int i = blockIdx.x * 256 + threadIdx.x;
  int stride = gridDim.x * 256;
  for (; i < n; i += stride) z[i] = 0.f;
}
__global__ void k_initu(unsigned* z, unsigned pat, int n){
  int i = blockIdx.x * 256 + threadIdx.x;
  int stride = gridDim.x * 256;
  for (; i < n; i += stride) z[i] = pat;
}

// ---------------------------------------------------------------- po layer 1
__global__ __launch_bounds__(256) void k_po1(
    const float* __restrict__ x, const float* __restrict__ w1, const float* __restrict__ b1,
    float* __restrict__ h1, float* __restrict__ s16, float* __restrict__ cmean){
  __shared__ __align__(16) float ws[512];
  __shared__ float bs[16];
  __shared__ float hs[256][17];
  __shared__ float xs[256][33];
  const int t = threadIdx.x;
  for (int i = t; i < 512; i += 256) ws[i] = w1[i];
  if (t < 16) bs[t] = b1[t];
  const int n = blockIdx.x * 256 + t;
  float xr[32];
  const float4* xp = (const float4*)(x + (size_t)n * 32);
#pragma unroll
  for (int i = 0; i < 8; ++i){
    float4 v = xp[i];
    xr[4*i+0] = v.x; xr[4*i+1] = v.y; xr[4*i+2] = v.z; xr[4*i+3] = v.w;
    xs[t][4*i+0] = v.x; xs[t][4*i+1] = v.y; xs[t][4*i+2] = v.z; xs[t][4*i+3] = v.w;
  }
  __syncthreads();
  float h[16];
#pragma unroll
  for (int o = 0; o < 16; ++o){
    float a = bs[o];
#pragma unroll
    for (int c = 0; c < 32; ++c) a = fmaf(ws[o*32 + c], xr[c], a);
    h[o] = a;
    hs[t][o] = a;
  }
  float4* hp = (float4*)(h1 + (size_t)n * 16);
#pragma unroll
  for (int i = 0; i < 4; ++i) hp[i] = make_float4(h[4*i], h[4*i+1], h[4*i+2], h[4*i+3]);
  __syncthreads();
  if (t < 16){
    float s = 0.f, q = 0.f;
    for (int r = 0; r < 256; ++r){ float v = hs[r][t]; s += v; q = fmaf(v, v, q); }
    atomicAdd(&s16[t], s);
    atomicAdd(&s16[16 + t], q);
  } else if (t >= 32 && t < 64){
    const int c = t - 32;
    float s = 0.f;
    for (int r = 0; r < 256; ++r) s += xs[r][c];
    const int b = blockIdx.x >> 5;
    atomicAdd(&cmean[b*32 + c], s);
  }
}

// ---------------------------------------------------------------- po layer 2
__global__ __launch_bounds__(256) void k_po2(
    const float* __restrict__ h1, const float* __restrict__ s16,
    const float* __restrict__ g1, const float* __restrict__ be1,
    const float* __restrict__ w2, const float* __restrict__ b2,
    float* __restrict__ pvec, float* __restrict__ s2v){
  __shared__ float sc[16], sh[16], w2s[16];
  __shared__ float as_[256];
  const int t = threadIdx.x;
  if (t < 16){
    float mu  = s16[t]    * (1.f/Nn);
    float var = fmaxf(s16[16+t] * (1.f/Nn) - mu*mu, 0.f);
    float s = g1[t] * rsqrtf(var + EPSBN);
    sc[t] = s; sh[t] = be1[t] - mu*s;
    w2s[t] = w2[t];
  }
  __syncthreads();
  const int n = blockIdx.x * 256 + t;
  const float* hp = h1 + (size_t)n * 16;
  float a = b2[0];
#pragma unroll
  for (int o = 0; o < 16; ++o)
    a = fmaf(fmaxf(hp[o]*sc[o] + sh[o], 0.f), w2s[o], a);
  pvec[n] = a;
  as_[t] = a;
  __syncthreads();
  if (t == 0){
    float s = 0.f, q = 0.f;
    for (int r = 0; r < 256; ++r){ float v = as_[r]; s += v; q = fmaf(v, v, q); }
    atomicAdd(&s2v[0], s); atomicAdd(&s2v[1], q);
  }
}

// ------------- per-segment: catt MLP + p softmax (MAX-SHIFTED) denom
__global__ __launch_bounds__(256) void k_pseg(
    float* __restrict__ pvec, const float* __restrict__ s2v,
    const float* __restrict__ g2, const float* __restrict__ be2,
    const float* __restrict__ cmean,
    const float* __restrict__ cw1, const float* __restrict__ cb1,
    const float* __restrict__ cw2, const float* __restrict__ cb2,
    float* __restrict__ catt, float* __restrict__ Zp){
  __shared__ float cm[32], t1[16], t2[32], red[256], scsh[2], pms;
  const int t = threadIdx.x, b = blockIdx.x;
  if (t == 0){
    float mu  = s2v[0] * (1.f/Nn);
    float var = fmaxf(s2v[1] * (1.f/Nn) - mu*mu, 0.f);
    float s = g2[0] * rsqrtf(var + EPSBN);
    scsh[0] = s; scsh[1] = be2[0] - mu*s;
  }
  if (t < 32) cm[t] = cmean[b*32 + t] * (1.f/Ln);
  __syncthreads();
  if (t < 16){
    float a = cb1[t];
#pragma unroll
    for (int c = 0; c < 32; ++c) a = fmaf(cw1[t*32 + c], cm[c], a);
    t1[t] = fmaxf(a, 0.f);
  }
  __syncthreads();
  if (t < 32){
    float a = cb2[t];
#pragma unroll
    for (int o = 0; o < 16; ++o) a = fmaf(cw2[t*16 + o], t1[o], a);
    t2[t] = fmaxf(a, 0.f);
  }
  __syncthreads();
  if (t < 32){
    float mx = -1e30f;
#pragma unroll
    for (int j = 0; j < 32; ++j) mx = fmaxf(mx, t2[j]);
    float sm = 0.f;
#pragma unroll
    for (int j = 0; j < 32; ++j) sm += expf(t2[j] - mx);
    catt[b*32 + t] = expf(t2[t] - mx) / sm;
  }
  const float sc = scsh[0], sh = scsh[1];
  float mx = 0.f;
  for (int i = 0; i < Ln/256; ++i){
    int n = b*Ln + i*256 + t;
    float p = fmaxf(pvec[n]*sc + sh, 0.f);
    mx = fmaxf(mx, p);
  }
  red[t] = mx; __syncthreads();
  for (int s = 128; s > 0; s >>= 1){
    if (t < s) red[t] = fmaxf(red[t], red[t+s]);
    __syncthreads();
  }
  if (t == 0) pms = red[0];
  __syncthreads();
  const float pm = pms;
  float acc = 0.f;
  for (int i = 0; i < Ln/256; ++i){
    int n = b*Ln + i*256 + t;
    float p = fmaxf(pvec[n]*sc + sh, 0.f);
    float e = expf(p - pm);
    pvec[n] = e;
    acc += e;
  }
  __syncthreads();
  red[t] = acc; __syncthreads();
  for (int s = 128; s > 0; s >>= 1){
    if (t < s) red[t] += red[t+s];
    __syncthreads();
  }
  if (t == 0) Zp[b] = red[0];
}

// ------------------------------------------- flt = gated x ; k1 = flt@k_w1^T (fp32)
__global__ __launch_bounds__(256) void k_fltk1(
    const float* __restrict__ x, const float* __restrict__ pvec,
    const float* __restrict__ Zp, const float* __restrict__ catt,
    const float* __restrict__ kw1, const float* __restrict__ kb1,
    float* __restrict__ flt, float* __restrict__ k1){
  __shared__ __align__(16) float ws[4096];
  __shared__ float kb[128], ca[32];
  const int t = threadIdx.x;
  for (int i = t; i < 4096; i += 256) ws[i] = kw1[i];
  if (t < 128) kb[t] = kb1[t];
  const int b = blockIdx.x >> 5;
  if (t < 32) ca[t] = catt[b*32 + t];
  __syncthreads();
  const int n = blockIdx.x * 256 + t;
  const float w = pvec[n] * (1e7f / Zp[b]);
  float fr[32];
  const float4* xp = (const float4*)(x + (size_t)n * 32);
  float4* fp = (float4*)(flt + (size_t)n * 32);
#pragma unroll
  for (int i = 0; i < 8; ++i){
    float4 v = xp[i];
    float4 o;
    o.x = v.x * w * ca[4*i+0];
    o.y = v.y * w * ca[4*i+1];
    o.z = v.z * w * ca[4*i+2];
    o.w = v.w * w * ca[4*i+3];
    fp[i] = o;
    fr[4*i+0] = o.x; fr[4*i+1] = o.y; fr[4*i+2] = o.z; fr[4*i+3] = o.w;
  }
  float4* kp = (float4*)(k1 + (size_t)n * 128);
#pragma unroll
  for (int og = 0; og < 32; ++og){
    float a[4];
#pragma unroll
    for (int p = 0; p < 4; ++p){
      const int o = og*4 + p;
      float acc = kb[o];
#pragma unroll
      for (int c = 0; c < 32; ++c) acc = fmaf(ws[o*32 + c], fr[c], acc);
      a[p] = acc;
    }
    kp[og] = make_float4(a[0], a[1], a[2], a[3]);
  }
}

// ---------------------------------------------------------------- k1 stats (128 ch)
__global__ __launch_bounds__(256) void k_k1s(const float* __restrict__ k1, float* __restrict__ sk1){
  __shared__ float rs_[256], rq_[256];
  const int t = threadIdx.x;
  const int c = t & 127, half = t >> 7;
  const size_t rowbase = (size_t)blockIdx.x * 512;
  float sum = 0.f, ssq = 0.f;
  for (int i = 0; i < 256; ++i){
    float v = k1[(rowbase + half + (size_t)i*2) * 128 + c];
    sum += v; ssq = fmaf(v, v, ssq);
  }
  rs_[t] = sum; rq_[t] = ssq;
  __syncthreads();
  if (t < 128){
    atomicAdd(&sk1[c],       rs_[t] + rs_[t+128]);
    atomicAdd(&sk1[128 + c], rq_[t] + rq_[t+128]);
  }
}

// ---------------- r1f = fp16(relu(bn1(k1))) — normalized, fp16-safe
__global__ __launch_bounds__(256) void k_r1w(
    const float* __restrict__ k1, const float* __restrict__ sk1,
    const float* __restrict__ kg1, const float* __restrict__ kbe1,
    f16* __restrict__ r1f){
  __shared__ float sc1[128], sh1[128];
  const int t = threadIdx.x;
  if (t < 128){
    float mu  = sk1[t]     * (1.f/Nn);
    float var = fmaxf(sk1[128+t] * (1.f/Nn) - mu*mu, 0.f);
    float s = kg1[t] * rsqrtf(var + EPSBN);
    sc1[t] = s; sh1[t] = kbe1[t] - mu*s;
  }
  __syncthreads();
  const size_t n = (size_t)blockIdx.x * 128 + (t >> 1);
  const int k0 = (t & 1) * 64;
  const float4* kp = (const float4*)(k1 + n*128 + k0);
#pragma unroll
  for (int u = 0; u < 8; ++u){
    float4 a = kp[2*u], b = kp[2*u+1];
    const int kk = k0 + u*8;
    half8 h;
    h[0] = (f16)fmaxf(a.x*sc1[kk+0] + sh1[kk+0], 0.f);
    h[1] = (f16)fmaxf(a.y*sc1[kk+1] + sh1[kk+1], 0.f);
    h[2] = (f16)fmaxf(a.z*sc1[kk+2] + sh1[kk+2], 0.f);
    h[3] = (f16)fmaxf(a.w*sc1[kk+3] + sh1[kk+3], 0.f);
    h[4] = (f16)fmaxf(b.x*sc1[kk+4] + sh1[kk+4], 0.f);
    h[5] = (f16)fmaxf(b.y*sc1[kk+5] + sh1[kk+5], 0.f);
    h[6] = (f16)fmaxf(b.z*sc1[kk+6] + sh1[kk+6], 0.f);
    h[7] = (f16)fmaxf(b.w*sc1[kk+7] + sh1[kk+7], 0.f);
    *(half8*)&r1f[n*128 + kk] = h;
  }
}

// ---------------- w2h = fp16(w2)
__global__ __launch_bounds__(256) void k_w2h(const float* __restrict__ kw2, f16* __restrict__ w2h){
  const int i = (blockIdx.x * 256 + threadIdx.x) * 4;
#pragma unroll
  for (int u = 0; u < 4; ++u) w2h[i+u] = (f16)kw2[i+u];
}

// ---------------- MFMA pass 1 v2: direct-global frags, stats + extrema, no LDS
__global__ __launch_bounds__(256) void k_k2m(
    const f16* __restrict__ r1f, const f16* __restrict__ w2h,
    float* __restrict__ S2, float* __restrict__ Q2,
    unsigned* __restrict__ amaxU, unsigned* __restrict__ aminU){
  const int t = threadIdx.x;
  const int b = blockIdx.z;
  const int c0g = blockIdx.y * 128;
  const size_t rowbase = (size_t)b * Ln + (size_t)blockIdx.x * 128;
  const int wid = t >> 6, lane = t & 63;
  const int wr = (wid & 1) * 64, wc = (wid >> 1) * 64;
  const int lrow = lane & 15, lkg = lane >> 4;
  f32x4 acc[4][4];
#pragma unroll
  for (int f = 0; f < 4; ++f)
#pragma unroll
    for (int g = 0; g < 4; ++g) acc[f][g] = (f32x4){0.f,0.f,0.f,0.f};
#pragma unroll
  for (int ks = 0; ks < 4; ++ks){
    half8 af[4], bf[4];
#pragma unroll
    for (int f = 0; f < 4; ++f)
      af[f] = *(const half8*)&r1f[(rowbase + wr + f*16 + lrow)*128 + ks*32 + lkg*8];
#pragma unroll
    for (int g = 0; g < 4; ++g)
      bf[g] = *(const half8*)&w2h[(size_t)(c0g + wc + g*16 + lrow)*128 + ks*32 + lkg*8];
#pragma unroll
    for (int f = 0; f < 4; ++f)
#pragma unroll
      for (int g = 0; g < 4; ++g)
        acc[f][g] = MFMA16(af[f], bf[g], acc[f][g]);
  }
#pragma unroll
  for (int g = 0; g < 4; ++g){
    float s = 0.f, q = 0.f, mx = -3.4e38f, mn = 3.4e38f;
#pragma unroll
    for (int f = 0; f < 4; ++f)
#pragma unroll
      for (int j = 0; j < 4; ++j){
        float a = acc[f][g][j];
        s += a; q = fmaf(a, a, q);
        mx = fmaxf(mx, a); mn = fminf(mn, a);
      }
    s += __shfl_xor(s, 16, 64);  s += __shfl_xor(s, 32, 64);
    q += __shfl_xor(q, 16, 64);  q += __shfl_xor(q, 32, 64);
    mx = fmaxf(mx, __shfl_xor(mx, 16, 64)); mx = fmaxf(mx, __shfl_xor(mx, 32, 64));
    mn = fminf(mn, __shfl_xor(mn, 16, 64)); mn = fminf(mn, __shfl_xor(mn, 32, 64));
    if (lane < 16){
      const int c = c0g + wc + g*16 + lane;
      atomicAdd(&S2[c], s);
      atomicAdd(&Q2[c], q);
      atomicMax(&amaxU[b*512 + c], f2ord(mx));
      atomicMin(&aminU[b*512 + c], f2ord(mn));
    }
  }
}

// --------------------------- finalize bn2 scale/shift per 512 ch (bias folded in)
__global__ __launch_bounds__(256) void k_k2fin(
    const float* __restrict__ S2, const float* __restrict__ Q2,
    const float* __restrict__ kb2, const float* __restrict__ kg2, const float* __restrict__ kbe2,
    float* __restrict__ sc2g, float* __restrict__ sh2g){
  const int c = blockIdx.x * 256 + threadIdx.x;
  float S = S2[c], Q = Q2[c], bb = kb2[c];
  float sum = S + (float)Nn * bb;
  float ssq = Q + 2.f*bb*S + (float)Nn * bb * bb;
  float mu  = sum * (1.f/Nn);
  float var = fmaxf(ssq * (1.f/Nn) - mu*mu, 0.f);
  float s = kg2[c] * rsqrtf(var + EPSBN);
  sc2g[c] = s;
  sh2g[c] = kbe2[c] + (bb - mu) * s;
}

// ---------------- pm[b,k] = max_r relu(bn2(k2)) from raw max/min extrema
__global__ void k_pmax(
    const unsigned* __restrict__ amaxU, const unsigned* __restrict__ aminU,
    const float* __restrict__ sc2g, const float* __restrict__ sh2g,
    float* __restrict__ pm){
  const int i = blockIdx.x * 256 + threadIdx.x;
  const int k = i & 511;
  float amax = ord2f(amaxU[i]), amin = ord2f(aminU[i]);
  float s = sc2g[k], h = sh2g[k];
  float p1 = fmaxf(amax*s + h, 0.f);
  float p2 = fmaxf(amin*s + h, 0.f);
  pm[i] = fmaxf(p1, p2);
}

// ---------------- MFMA pass 2 v3: GEMM (direct-global, bit-identical) + PV via MFMA
// grid (8,4,16); LDS e2t[128][136]f16 + flth[32][136]f16 = 43.5KB -> 3 blocks/CU.
__global__ __launch_bounds__(256) void k_poolm(
    const f16* __restrict__ r1f, const f16* __restrict__ w2h,
    const float* __restrict__ flt,
    const float* __restrict__ sc2g, const float* __restrict__ sh2g,
    const float* __restrict__ pm,
    float* __restrict__ poolAcc, float* __restrict__ Z2){
  __shared__ __align__(16) char U[43520];
  f16* e2t  = (f16*)U;             // [col 128][136] row-contig
  f16* flth = (f16*)(U + 34816);   // [ch 32][136]  row-contig, scaled 2^-9
  const int t = threadIdx.x;
  const int b = blockIdx.z;
  const int c0g = blockIdx.y * 128;
  const int wid = t >> 6, lane = t & 63;
  const int wr = (wid & 1) * 64, wc = (wid >> 1) * 64;
  const int lrow = lane & 15, lkg = lane >> 4;
  float sc2r[4], sh2r[4], pmr[4];
#pragma unroll
  for (int g = 0; g < 4; ++g){
    const int c = c0g + wc + g*16 + lrow;
    sc2r[g] = sc2g[c]; sh2r[g] = sh2g[c]; pmr[g] = pm[b*512 + c];
  }
  f32x4 pv[2][2];
#pragma unroll
  for (int m = 0; m < 2; ++m)
#pragma unroll
    for (int n = 0; n < 2; ++n) pv[m][n] = (f32x4){0.f,0.f,0.f,0.f};
  float zacc[4] = {0.f,0.f,0.f,0.f};
  for (int rt = 0; rt < 8; ++rt){
    const size_t rowbase = (size_t)b * Ln + ((size_t)blockIdx.x * 8 + rt) * 128;
    // GEMM from global (bit-identical K-chain to k_k2m)
    f32x4 acc[4][4];
#pragma unroll
    for (int f = 0; f < 4; ++f)
#pragma unroll
      for (int g = 0; g < 4; ++g) acc[f][g] = (f32x4){0.f,0.f,0.f,0.f};
#pragma unroll
    for (int ks = 0; ks < 4; ++ks){
      half8 af[4], bf[4];
#pragma unroll
      for (int f = 0; f < 4; ++f)
        af[f] = *(const half8*)&r1f[(rowbase + wr + f*16 + lrow)*128 + ks*32 + lkg*8];
#pragma unroll
      for (int g = 0; g < 4; ++g)
        bf[g] = *(const half8*)&w2h[(size_t)(c0g + wc + g*16 + lrow)*128 + ks*32 + lkg*8];
#pragma unroll
      for (int f = 0; f < 4; ++f)
#pragma unroll
        for (int g = 0; g < 4; ++g)
          acc[f][g] = MFMA16(af[f], bf[g], acc[f][g]);
    }
    __syncthreads();                  // prev tile's PV reads retired
    // exp -> fp16, transpose-write e2t[col][row] (half4), Z from rounded e2
#pragma unroll
    for (int f = 0; f < 4; ++f)
#pragma unroll
      for (int g = 0; g < 4; ++g){
        half4 hp;
#pragma unroll
        for (int j = 0; j < 4; ++j){
          float p = fmaxf(acc[f][g][j]*sc2r[g] + sh2r[g], 0.f);
          f16 h = (f16)expf(p - pmr[g]);
          hp[j] = h;
          zacc[g] += (float)h;
        }
        *(half4*)&e2t[(wc + g*16 + lrow)*136 + wr + f*16 + lkg*4] = hp;
      }
    // stage flth[ch][row] = fp16(flt * 2^-9)
#pragma unroll
    for (int i = 0; i < 4; ++i){
      int lin = t + i*256;
      int r = lin >> 3, c4 = lin & 7;
      float4 v = *(const float4*)&flt[(rowbase + r)*32 + c4*4];
      flth[(c4*4+0)*136 + r] = (f16)(v.x * 0.001953125f);
      flth[(c4*4+1)*136 + r] = (f16)(v.y * 0.001953125f);
      flth[(c4*4+2)*136 + r] = (f16)(v.z * 0.001953125f);
      flth[(c4*4+3)*136 + r] = (f16)(v.w * 0.001953125f);
    }
    __syncthreads();                  // e2t/flth visible
    // PV: pooled[c][ch] += e2^T @ flt_scaled  (M=128 c, N=32 ch, K=128 rows)
#pragma unroll
    for (int ks = 0; ks < 4; ++ks){
      half8 pa[2], pb[2];
#pragma unroll
      for (int m = 0; m < 2; ++m)
        pa[m] = *(const half8*)&e2t[((wid*2 + m)*16 + lrow)*136 + ks*32 + lkg*8];
#pragma unroll
      for (int n = 0; n < 2; ++n)
        pb[n] = *(const half8*)&flth[(n*16 + lrow)*136 + ks*32 + lkg*8];
#pragma unroll
      for (int m = 0; m < 2; ++m)
#pragma unroll
        for (int n = 0; n < 2; ++n)
          pv[m][n] = MFMA16(pa[m], pb[n], pv[m][n]);
    }
  }
  // single dump: pooled (x512 undoes flt scale), Z via shfl-reduce
#pragma unroll
  for (int m = 0; m < 2; ++m)
#pragma unroll
    for (int n = 0; n < 2; ++n)
#pragma unroll
      for (int j = 0; j < 4; ++j){
        const int c  = c0g + (wid*2 + m)*16 + lkg*4 + j;
        const int ch = n*16 + lrow;
        atomicAdd(&poolAcc[((size_t)b*512 + c)*32 + ch], pv[m][n][j] * 512.f);
      }
#pragma unroll
  for (int g = 0; g < 4; ++g){
    float z = zacc[g];
    z += __shfl_xor(z, 16, 64);
    z += __shfl_xor(z, 32, 64);
    if (lane < 16) atomicAdd(&Z2[b*512 + c0g + wc + g*16 + lane], z);
  }
}

// ---------------- FALLBACK pass 1 (fp32 tiled GEMM stats)
__global__ __launch_bounds__(256) void k_k2sx(
    const float* __restrict__ k1, const float* __restrict__ kw2,
    const float* __restrict__ sk1, const float* __restrict__ kg1, const float* __restrict__ kbe1,
    float* __restrict__ S2, float* __restrict__ Q2,
    unsigned* __restrict__ amaxU, unsigned* __restrict__ aminU){
  __shared__ float sc1[128], sh1[128];
  __shared__ __align__(16) float r1t[64][68];
  __shared__ __align__(16) float w2t[64][68];
  const int t = threadIdx.x;
  const int chunk = blockIdx.x;
  const int cg    = blockIdx.y;
  const int b     = blockIdx.z;
  const int c0g = cg * 64;
  const size_t rowbase = (size_t)b * Ln + (size_t)chunk * 512;
  if (t < 128){
    float mu  = sk1[t]     * (1.f/Nn);
    float var = fmaxf(sk1[128+t] * (1.f/Nn) - mu*mu, 0.f);
    float s = kg1[t] * rsqrtf(var + EPSBN);
    sc1[t] = s; sh1[t] = kbe1[t] - mu*s;
  }
  const int ig = t & 15, jg = t >> 4;
  const int rr = t >> 2;
  const int ka4 = (t & 3) * 4;
  float csum[4] = {0.f,0.f,0.f,0.f}, cssq[4] = {0.f,0.f,0.f,0.f};
  float cmax[4] = {-3.4e38f,-3.4e38f,-3.4e38f,-3.4e38f};
  float cmin[4] = { 3.4e38f, 3.4e38f, 3.4e38f, 3.4e38f};
  for (int st = 0; st < 8; ++st){
    const size_t rb = rowbase + st*64;
    float acc[4][4];
#pragma unroll
    for (int i = 0; i < 4; ++i)
#pragma unroll
      for (int j = 0; j < 4; ++j) acc[i][j] = 0.f;
    for (int kb = 0; kb < 2; ++kb){
      __syncthreads();
#pragma unroll
      for (int u = 0; u < 4; ++u){
        const int kk = ka4 + u*16;
        const int ch = kb*64 + kk;
        float4 v = *(const float4*)&k1[(rb + rr)*128 + ch];
        r1t[kk+0][rr] = fmaxf(v.x*sc1[ch+0] + sh1[ch+0], 0.f);
        r1t[kk+1][rr] = fmaxf(v.y*sc1[ch+1] + sh1[ch+1], 0.f);
        r1t[kk+2][rr] = fmaxf(v.z*sc1[ch+2] + sh1[ch+2], 0.f);
        r1t[kk+3][rr] = fmaxf(v.w*sc1[ch+3] + sh1[ch+3], 0.f);
        float4 wv = *(const float4*)&kw2[(size_t)(c0g + rr)*128 + ch];
        w2t[kk+0][rr] = wv.x; w2t[kk+1][rr] = wv.y;
        w2t[kk+2][rr] = wv.z; w2t[kk+3][rr] = wv.w;
      }
      __syncthreads();
#pragma unroll 4
      for (int kk = 0; kk < 64; ++kk){
        float4 av = *(const float4*)&r1t[kk][ig*4];
        float4 bv = *(const float4*)&w2t[kk][jg*4];
        acc[0][0]=fmaf(av.x,bv.x,acc[0][0]); acc[0][1]=fmaf(av.x,bv.y,acc[0][1]);
        acc[0][2]=fmaf(av.x,bv.z,acc[0][2]); acc[0][3]=fmaf(av.x,bv.w,acc[0][3]);
        acc[1][0]=fmaf(av.y,bv.x,acc[1][0]); acc[1][1]=fmaf(av.y,bv.y,acc[1][1]);
        acc[1][2]=fmaf(av.y,bv.z,acc[1][2]); acc[1][3]=fmaf(av.y,bv.w,acc[1][3]);
        acc[2][0]=fmaf(av.z,bv.x,acc[2][0]); acc[2][1]=fmaf(av.z,bv.y,acc[2][1]);
        acc[2][2]=fmaf(av.z,bv.z,acc[2][2]); acc[2][3]=fmaf(av.z,bv.w,acc[2][3]);
        acc[3][0]=fmaf(av.w,bv.x,acc[3][0]); acc[3][1]=fmaf(av.w,bv.y,acc[3][1]);
        acc[3][2]=fmaf(av.w,bv.z,acc[3][2]); acc[3][3]=fmaf(av.w,bv.w,acc[3][3]);
      }
    }
#pragma unroll
    for (int j = 0; j < 4; ++j){
      float s4 = 0.f, q4 = 0.f;
#pragma unroll
      for (int i = 0; i < 4; ++i){
        float a = acc[i][j];
        s4 += a; q4 = fmaf(a, a, q4);
        cmax[j] = fmaxf(cmax[j], a);
        cmin[j] = fminf(cmin[j], a);
      }
      csum[j] += s4; cssq[j] += q4;
    }
  }
  float* redS  = &r1t[0][0];
  float* redQ  = &r1t[0][0] + 1024;
  float* redMx = &w2t[0][0];
  float* redMn = &w2t[0][0] + 1024;
  __syncthreads();
#pragma unroll
  for (int j = 0; j < 4; ++j){
    redS [ig*64 + jg*4 + j] = csum[j];
    redQ [ig*64 + jg*4 + j] = cssq[j];
    redMx[ig*64 + jg*4 + j] = cmax[j];
    redMn[ig*64 + jg*4 + j] = cmin[j];
  }
  __syncthreads();
  if (t < 64){
    float s = 0.f, q = 0.f, mx = -3.4e38f, mn = 3.4e38f;
#pragma unroll
    for (int i = 0; i < 16; ++i){
      s += redS[i*64 + t]; q += redQ[i*64 + t];
      mx = fmaxf(mx, redMx[i*64 + t]); mn = fminf(mn, redMn[i*64 + t]);
    }
    atomicAdd(&S2[c0g + t], s);
    atomicAdd(&Q2[c0g + t], q);
    atomicMax(&amaxU[b*512 + c0g + t], f2ord(mx));
    atomicMin(&aminU[b*512 + c0g + t], f2ord(mn));
  }
}

// ---------------- FALLBACK pass 2 (fp32 tiled GEMM + pool)
__global__ __launch_bounds__(256) void k_poolx(
    const float* __restrict__ k1, const float* __restrict__ flt,
    const float* __restrict__ kw2,
    const float* __restrict__ sk1, const float* __restrict__ kg1, const float* __restrict__ kbe1,
    const float* __restrict__ sc2g, const float* __restrict__ sh2g,
    const float* __restrict__ pm,
    float* __restrict__ poolAcc, float* __restrict__ Z2){
  __shared__ float sc1[128], sh1[128], sc2[64], sh2[64], pmL[64];
  __shared__ __align__(16) float r1t[64][68];
  __shared__ __align__(16) float w2t[64][68];
  __shared__ __align__(16) float e2s[64][68];
  __shared__ __align__(16) float flts[64][36];
  const int t = threadIdx.x;
  const int chunk = blockIdx.x;
  const int cg    = blockIdx.y;
  const int b     = blockIdx.z;
  const int c0g = cg * 64;
  const size_t rowbase = (size_t)b * Ln + (size_t)chunk * 512;
  if (t < 128){
    float mu  = sk1[t]     * (1.f/Nn);
    float var = fmaxf(sk1[128+t] * (1.f/Nn) - mu*mu, 0.f);
    float s = kg1[t] * rsqrtf(var + EPSBN);
    sc1[t] = s; sh1[t] = kbe1[t] - mu*s;
  } else if (t < 192){
    int c = t - 128;
    sc2[c] = sc2g[c0g + c];
    sh2[c] = sh2g[c0g + c];
    pmL[c] = pm[b*512 + c0g + c];
  }
  const int ig = t & 15, jg = t >> 4;
  const int cq = t & 15, hq = t >> 4;
  const int rr = t >> 2;
  const int ka4 = (t & 3) * 4;
  float pacc[4][2] = {{0.f,0.f},{0.f,0.f},{0.f,0.f},{0.f,0.f}};
  float zacc[4] = {0.f,0.f,0.f,0.f};
  for (int st = 0; st < 8; ++st){
    const size_t rb = rowbase + st*64;
    __syncthreads();
#pragma unroll
    for (int i = 0; i < 2; ++i){
      int lin = t + i*256;
      int r = lin >> 3, c4 = lin & 7;
      *(float4*)&flts[r][c4*4] = *(const float4*)&flt[(rb + r)*32 + c4*4];
    }
    float acc[4][4];
#pragma unroll
    for (int i = 0; i < 4; ++i)
#pragma unroll
      for (int j = 0; j < 4; ++j) acc[i][j] = 0.f;
    for (int kb = 0; kb < 2; ++kb){
      __syncthreads();
#pragma unroll
      for (int u = 0; u < 4; ++u){
        const int kk = ka4 + u*16;
        const int ch = kb*64 + kk;
        float4 v = *(const float4*)&k1[(rb + rr)*128 + ch];
        r1t[kk+0][rr] = fmaxf(v.x*sc1[ch+0] + sh1[ch+0], 0.f);
        r1t[kk+1][rr] = fmaxf(v.y*sc1[ch+1] + sh1[ch+1], 0.f);
        r1t[kk+2][rr] = fmaxf(v.z*sc1[ch+2] + sh1[ch+2], 0.f);
        r1t[kk+3][rr] = fmaxf(v.w*sc1[ch+3] + sh1[ch+3], 0.f);
        float4 wv = *(const float4*)&kw2[(size_t)(c0g + rr)*128 + ch];
        w2t[kk+0][rr] = wv.x; w2t[kk+1][rr] = wv.y;
        w2t[kk+2][rr] = wv.z; w2t[kk+3][rr] = wv.w;
      }
      __syncthreads();
#pragma unroll 4
      for (int kk = 0; kk < 64; ++kk){
        float4 av = *(const float4*)&r1t[kk][ig*4];
        float4 bv = *(const float4*)&w2t[kk][jg*4];
        acc[0][0]=fmaf(av.x,bv.x,acc[0][0]); acc[0][1]=fmaf(av.x,bv.y,acc[0][1]);
        acc[0][2]=fmaf(av.x,bv.z,acc[0][2]); acc[0][3]=fmaf(av.x,bv.w,acc[0][3]);
        acc[1][0]=fmaf(av.y,bv.x,acc[1][0]); acc[1][1]=fmaf(av.y,bv.y,acc[1][1]);
        acc[1][2]=fmaf(av.y,bv.z,acc[1][2]); acc[1][3]=fmaf(av.y,bv.w,acc[1][3]);
        acc[2][0]=fmaf(av.z,bv.x,acc[2][0]); acc[2][1]=fmaf(av.z,bv.y,acc[2][1]);
        acc[2][2]=fmaf(av.z,bv.z,acc[2][2]); acc[2][3]=fmaf(av.z,bv.w,acc[2][3]);
        acc[3][0]=fmaf(av.w,bv.x,acc[3][0]); acc[3][1]=fmaf(av.w,bv.y,acc[3][1]);
        acc[3][2]=fmaf(av.w,bv.z,acc[3][2]); acc[3][3]=fmaf(av.w,bv.w,acc[3][3]);
      }
    }
#pragma unroll
    for (int i = 0; i < 4; ++i){
      int r = ig*4 + i;
#pragma unroll
      for (int j = 0; j < 4; ++j){
        int c = jg*4 + j;
        float p = fmaxf(acc[i][j]*sc2[c] + sh2[c], 0.f);
        e2s[r][c] = expf(p - pmL[c]);
      }
    }
    __syncthreads();
#pragma unroll 4
    for (int r = 0; r < 64; ++r){
      float4 ev = *(const float4*)&e2s[r][cq*4];
      float f0 = flts[r][hq*2], f1 = flts[r][hq*2 + 1];
      pacc[0][0]=fmaf(ev.x,f0,pacc[0][0]); pacc[0][1]=fmaf(ev.x,f1,pacc[0][1]);
      pacc[1][0]=fmaf(ev.y,f0,pacc[1][0]); pacc[1][1]=fmaf(ev.y,f1,pacc[1][1]);
      pacc[2][0]=fmaf(ev.z,f0,pacc[2][0]); pacc[2][1]=fmaf(ev.z,f1,pacc[2][1]);
      pacc[3][0]=fmaf(ev.w,f0,pacc[3][0]); pacc[3][1]=fmaf(ev.w,f1,pacc[3][1]);
      if (hq == 0){ zacc[0]+=ev.x; zacc[1]+=ev.y; zacc[2]+=ev.z; zacc[3]+=ev.w; }
    }
  }
#pragma unroll
  for (int ci = 0; ci < 4; ++ci){
    int c = c0g + cq*4 + ci;
#pragma unroll
    for (int hj = 0; hj < 2; ++hj)
      atomicAdd(&poolAcc[((size_t)b*512 + c)*32 + hq*2 + hj], pacc[ci][hj]);
    if (hq == 0) atomicAdd(&Z2[b*512 + c], zacc[ci]);
  }
}

// ---------------------------------------------------------------- out2 finalize
__global__ __launch_bounds__(256) void k_out2(
    const float* __restrict__ poolAcc, const float* __restrict__ Z2, float* __restrict__ out2){
  const int i = blockIdx.x * 256 + threadIdx.x;
  const int k = (i >> 5) & 511;
  const int b = i >> 14;
  out2[i] = poolAcc[i] / (Z2[b*512 + k] * (float)Ln);
}

// ---------------------------------------------------------------- FC1 (+BN over b, relu)
__global__ __launch_bounds__(256) void k_fc1(
    const float* __restrict__ out2, const float* __restrict__ w1, const float* __restrict__ b1,
    const float* __restrict__ g1, const float* __restrict__ be1, float* __restrict__ rfc1){
  __shared__ float red[256];
  __shared__ float pre[16];
  __shared__ float scsh[2];
  const int ch = blockIdx.x;
  const int t  = threadIdx.x;
  float acc[16];
#pragma unroll
  for (int bb = 0; bb < 16; ++bb) acc[bb] = 0.f;
  for (int k = t; k < 16384; k += 256){
    float w = w1[(size_t)ch*16384 + k];
#pragma unroll
    for (int bb = 0; bb < 16; ++bb)
      acc[bb] = fmaf(out2[(size_t)bb*16384 + k], w, acc[bb]);
  }
  for (int bb = 0; bb < 16; ++bb){
    red[t] = acc[bb]; __syncthreads();
    for (int s = 128; s > 0; s >>= 1){
      if (t < s) red[t] += red[t+s];
      __syncthreads();
    }
    if (t == 0) pre[bb] = red[0] + b1[ch];
    __syncthreads();
  }
  if (t == 0){
    float m = 0.f, qv = 0.f;
#pragma unroll
    for (int bb = 0; bb < 16; ++bb){ float v = pre[bb]; m += v; qv = fmaf(v, v, qv); }
    m *= (1.f/16.f); qv = fmaxf(qv*(1.f/16.f) - m*m, 0.f);
    float s = g1[ch] * rsqrtf(qv + EPSBN);
    scsh[0] = s; scsh[1] = be1[ch] - m*s;
  }
  __syncthreads();
  if (t < 16)
    rfc1[(size_t)t*512 + ch] = fmaxf(pre[t]*scsh[0] + scsh[1], 0.f);
}

// ---------------------------------------------------------------- FC2 (+BN over b, no relu)
__global__ __launch_bounds__(128) void k_fc2(
    const float* __restrict__ rfc1, const float* __restrict__ w2, const float* __restrict__ b2,
    const float* __restrict__ g2, const float* __restrict__ be2, float* __restrict__ rfc2){
  __shared__ float pre[8][16];
  __shared__ float scB[8], shB[8];
  const int t = threadIdx.x;
  const int bb = t & 15, jl = t >> 4;
  const int ch = blockIdx.x*8 + jl;
  float a = b2[ch];
  for (int k = 0; k < 512; ++k)
    a = fmaf(rfc1[(size_t)bb*512 + k], w2[(size_t)ch*512 + k], a);
  pre[jl][bb] = a;
  __syncthreads();
  if (t < 8){
    float m = 0.f, q = 0.f;
#pragma unroll
    for (int i = 0; i < 16; ++i){ float v = pre[t][i]; m += v; q = fmaf(v, v, q); }
    m *= (1.f/16.f); q = fmaxf(q*(1.f/16.f) - m*m, 0.f);
    float s = g2[blockIdx.x*8 + t] * rsqrtf(q + EPSBN);
    scB[t] = s; shB[t] = be2[blockIdx.x*8 + t] - m*s;
  }
  __syncthreads();
  rfc2[(size_t)bb*256 + ch] = pre[jl][bb]*scB[jl] + shB[jl];
}

// ---------------------------------------------------------------- final L2 normalize
__global__ __launch_bounds__(256) void k_fin(const float* __restrict__ rfc2, float* __restrict__ out){
  __shared__ float red[256];
  const int b = blockIdx.x, t = threadIdx.x;
  float v = rfc2[b*256 + t];
  red[t] = v*v; __syncthreads();
  for (int s = 128; s > 0; s >>= 1){
    if (t < s) red[t] += red[t+s];
    __syncthreads();
  }
  float nrm = sqrtf(red[0]);
  out[b*256 + t] = v / fmaxf(nrm, 1e-12f);
}

// ---------------- CONDITIONAL diagnostic (3000+code), clobbers only on failure
__global__ void k_diag3(
    const float* __restrict__ out2, const float* __restrict__ rfc1,
    const float* __restrict__ rfc2, float* __restrict__ out){
  if (blockIdx.x != 0 || threadIdx.x != 0) return;
  auto differs = [](float a, float b)->bool{
    return isfinite(a) && isfinite(b) &&
           fabsf(a - b) > 1e-7f*(fabsf(a) + fabsf(b)) + 1e-30f;
  };
  int code = 0;
  { bool ok = true;
    for (int j = 0; j < 512; ++j){
      size_t idx = ((size_t)j * 16411u + 13u) % ((size_t)Bn * 16384u);
      ok = ok && isfinite(out2[idx]);
    }
    if (ok) code += 128; }
  if (differs(out2[100*32 + 5], out2[100*32 + 17])) code += 64;
  if (differs(out2[100*32 + 5], out2[300*32 + 5])) code += 32;
  if (differs(out2[100*32 + 5], out2[(size_t)8*16384 + 100*32 + 5])) code += 16;
  { bool any = false;
    for (int i = 0; i < 512; ++i) if (fabsf(rfc1[i]) > 0.f){ any = true; break; }
    if (any) code += 8; }
  { bool any = false;
    for (int ch = 0; ch < 64; ++ch)
      any = any || differs(rfc1[ch], rfc1[(size_t)8*512 + ch]);
    if (any) code += 4; }
  { bool any = false;
    for (int t2 = 0; t2 < 256; ++t2)
      if (fabsf(rfc2[t2] - rfc2[8*256 + t2]) > 1e-12f){ any = true; break; }
    if (any) code += 2; }
  if (fabsf(out2[100*32 + 5]) > 1e-30f) code += 1;

  if (code != 255) out[0] = 3000.f + (float)code;
}

// ================================================================ host launcher
extern "C" void kernel_launch(void* const* d_in, const int* in_sizes, int n_in,
                              void* d_out, int out_size, void* d_ws, size_t ws_size,
                              hipStream_t stream){
  (void)in_sizes; (void)n_in; (void)out_size;
  const float* x      = (const float*)d_in[0];
  const float* po_w1  = (const float*)d_in[2];
  const float* po_b1  = (const float*)d_in[3];
  const float* po_g1  = (const float*)d_in[4];
  const float* po_be1 = (const float*)d_in[5];
  const float* po_w2  = (const float*)d_in[6];
  const float* po_b2  = (const float*)d_in[7];
  const float* po_g2  = (const float*)d_in[8];
  const float* po_be2 = (const float*)d_in[9];
  const float* ch_w1  = (const float*)d_in[10];
  const float* ch_b1  = (const float*)d_in[11];
  const float* ch_w2  = (const float*)d_in[12];
  const float* ch_b2  = (const float*)d_in[13];
  const float* k_w1   = (const float*)d_in[14];
  const float* k_b1   = (const float*)d_in[15];
  const float* k_g1   = (const float*)d_in[16];
  const float* k_be1  = (const float*)d_in[17];
  const float* k_w2   = (const float*)d_in[18];
  const float* k_b2   = (const float*)d_in[19];
  const float* k_g2   = (const float*)d_in[20];
  const float* k_be2  = (const float*)d_in[21];
  const float* fc_w1  = (const float*)d_in[22];
  const float* fc_b1  = (const float*)d_in[23];
  const float* fc_g1  = (const float*)d_in[24];
  const float* fc_be1 = (const float*)d_in[25];
  const float* fc_w2  = (const float*)d_in[26];
  const float* fc_b2  = (const float*)d_in[27];
  const float* fc_g2  = (const float*)d_in[28];
  const float* fc_be2 = (const float*)d_in[29];

  char* base = (char*)d_ws;
  size_t off = 0;
  auto alloc = [&](size_t bytes) -> char* {
    char* p = base + off;
    off = (off + bytes + 255) & ~(size_t)255;
    return p;
  };
  float* h1   = (float*)alloc((size_t)Nn * 16 * 4);
  float* pvec = (float*)alloc((size_t)Nn * 4);
  float* flt  = (float*)alloc((size_t)Nn * 32 * 4);
  float* k1   = (float*)alloc((size_t)Nn * 128 * 4);
  // ---- zeroed accumulator region (contiguous) ----
  char* zbase = base + off;
  float*    s16     = (float*)alloc(32 * 4);
  float*    s2v     = (float*)alloc(2 * 4);
  float*    cmean   = (float*)alloc(512 * 4);
  float*    sk1     = (float*)alloc(256 * 4);
  float*    S2      = (float*)alloc(512 * 4);
  float*    Q2      = (float*)alloc(512 * 4);
  float*    Z2      = (float*)alloc((size_t)Bn * 512 * 4);
  float*    poolAcc = (float*)alloc((size_t)Bn * 512 * 32 * 4);
  unsigned* amaxU   = (unsigned*)alloc((size_t)Bn * 512 * 4);
  char* zend = base + off;
  // ---- 0xFFFFFFFF-init region ----
  unsigned* aminU = (unsigned*)alloc((size_t)Bn * 512 * 4);
  // ---- written-before-read buffers ----
  float* catt  = (float*)alloc(512 * 4);
  float* Zp    = (float*)alloc(16 * 4);
  float* sc2g  = (float*)alloc(512 * 4);
  float* sh2g  = (float*)alloc(512 * 4);
  float* pm    = (float*)alloc((size_t)Bn * 512 * 4);
  float* out2  = (float*)alloc((size_t)Bn * 16384 * 4);
  float* rfc1  = (float*)alloc((size_t)Bn * 512 * 4);
  float* rfc2  = (float*)alloc((size_t)Bn * 256 * 4);
  if (off > ws_size) return;  // base workspace too small -> visible failure
  // ---- optional fp16 region (r1f 33.5MB + w2h 128KB) with fp32 fallback ----
  f16* r1f = nullptr; f16* w2h = nullptr;
  {
    size_t save = off;
    char* p1 = alloc((size_t)Nn * 128 * 2);
    char* p2 = alloc((size_t)512 * 128 * 2);
    if (off <= ws_size){ r1f = (f16*)p1; w2h = (f16*)p2; }
    else off = save;
  }

  const int nzero = (int)((zend - zbase) / 4);
  hipLaunchKernelGGL(k_init,   dim3(64), dim3(256), 0, stream, (float*)zbase, nzero);
  hipLaunchKernelGGL(k_initu,  dim3(32), dim3(256), 0, stream, aminU, 0xFFFFFFFFu, Bn*512);
  hipLaunchKernelGGL(k_po1,    dim3(Nn/256), dim3(256), 0, stream, x, po_w1, po_b1, h1, s16, cmean);
  hipLaunchKernelGGL(k_po2,    dim3(Nn/256), dim3(256), 0, stream, h1, s16, po_g1, po_be1, po_w2, po_b2, pvec, s2v);
  hipLaunchKernelGGL(k_pseg,   dim3(Bn), dim3(256), 0, stream, pvec, s2v, po_g2, po_be2, cmean,
                     ch_w1, ch_b1, ch_w2, ch_b2, catt, Zp);
  hipLaunchKernelGGL(k_fltk1,  dim3(Nn/256), dim3(256), 0, stream, x, pvec, Zp, catt, k_w1, k_b1, flt, k1);
  hipLaunchKernelGGL(k_k1s,    dim3(Nn/512), dim3(256), 0, stream, k1, sk1);
  if (r1f){
    hipLaunchKernelGGL(k_r1w,  dim3(Nn/128), dim3(256), 0, stream, k1, sk1, k_g1, k_be1, r1f);
    hipLaunchKernelGGL(k_w2h,  dim3(64), dim3(256), 0, stream, k_w2, w2h);
    hipLaunchKernelGGL(k_k2m,  dim3(64, 4, Bn), dim3(256), 0, stream, r1f, w2h, S2, Q2, amaxU, aminU);
    hipLaunchKernelGGL(k_k2fin, dim3(2), dim3(256), 0, stream, S2, Q2, k_b2, k_g2, k_be2, sc2g, sh2g);
    hipLaunchKernelGGL(k_pmax, dim3((Bn*512)/256), dim3(256), 0, stream, amaxU, aminU, sc2g, sh2g, pm);
    hipLaunchKernelGGL(k_poolm, dim3(8, 4, Bn), dim3(256), 0, stream, r1f, w2h, flt,
                       sc2g, sh2g, pm, poolAcc, Z2);
  } else {
    hipLaunchKernelGGL(k_k2sx, dim3(16, 8, Bn), dim3(256), 0, stream, k1, k_w2, sk1, k_g1, k_be1,
                       S2, Q2, amaxU, aminU);
    hipLaunchKernelGGL(k_k2fin, dim3(2), dim3(256), 0, stream, S2, Q2, k_b2, k_g2, k_be2, sc2g, sh2g);
    hipLaunchKernelGGL(k_pmax, dim3((Bn*512)/256), dim3(256), 0, stream, amaxU, aminU, sc2g, sh2g, pm);
    hipLaunchKernelGGL(k_poolx, dim3(16, 8, Bn), dim3(256), 0, stream, k1, flt, k_w2, sk1, k_g1, k_be1,
                       sc2g, sh2g, pm, poolAcc, Z2);
  }
  hipLaunchKernelGGL(k_out2,   dim3((Bn*16384)/256), dim3(256), 0, stream, poolAcc, Z2, out2);
  hipLaunchKernelGGL(k_fc1,    dim3(512), dim3(256), 0, stream, out2, fc_w1, fc_b1, fc_g1, fc_be1, rfc1);
  hipLaunchKernelGGL(k_fc2,    dim3(32), dim3(128), 0, stream, rfc1, fc_w2, fc_b2, fc_g2, fc_be2, rfc2);
  hipLaunchKernelGGL(k_fin,    dim3(Bn), dim3(256), 0, stream, rfc2, (float*)d_out);
  hipLaunchKernelGGL(k_diag3,  dim3(1), dim3(64), 0, stream, out2, rfc1, rfc2, (float*)d_out);
}